// Round 5
// baseline (530.115 us; speedup 1.0000x reference)
//
#include <hip/hip_runtime.h>
#include <cstdint>
#include <cstddef>

typedef unsigned short ushort_t;
typedef __bf16 bf16x8 __attribute__((ext_vector_type(8)));
typedef float f32x4 __attribute__((ext_vector_type(4)));

__device__ __forceinline__ float b2f(ushort_t u) {
    return __uint_as_float(((unsigned int)u) << 16);
}
__device__ __forceinline__ ushort_t f2b(float f) {
    __bf16 h = (__bf16)f;  // RNE
    return *(ushort_t*)&h;
}
// bf16 pair unpack from packed uint (little-endian: lo ushort = even channel)
__device__ __forceinline__ float lo16(unsigned int u) { return __uint_as_float(u << 16); }
__device__ __forceinline__ float hi16(unsigned int u) { return __uint_as_float(u & 0xffff0000u); }
__device__ __forceinline__ unsigned int pack2(float a, float b) {
    return ((unsigned int)f2b(b) << 16) | (unsigned int)f2b(a);
}

// stage 8 contiguous bf16 elements into LDS (16B copy)
__device__ __forceinline__ void stage8(const ushort_t* __restrict__ g, ushort_t* s) {
    *(float4*)s = *(const float4*)g;
}

// ---------------- weight transpose+convert: WT[n][k] = bf16(W[k][n]) ----------------
__global__ __launch_bounds__(256) void transpose_kernel(const float* __restrict__ W,
                                                        ushort_t* __restrict__ WT,
                                                        int K, int N2) {
    int id = blockIdx.x * 256 + threadIdx.x;
    if (id >= K * N2) return;
    int n = id / K, k = id - n * K;
    WT[id] = f2b(W[k * N2 + n]);
}

// ---------------- fold attention vectors through W1: was/wad[h][c] (layer 1 only) ----------
// was[h][c] = sum_k W1[c][h*64+k] * a_src[h][k]  (W1 is [128][256] fp32, a_src [4][64])
__global__ __launch_bounds__(256) void prep_asad_kernel(const float* __restrict__ W1,
                                                        const float* __restrict__ a_src,
                                                        const float* __restrict__ a_dst,
                                                        float* __restrict__ was,
                                                        float* __restrict__ wad) {
#pragma unroll
    for (int it = 0; it < 4; it++) {
        int id = it * 256 + threadIdx.x;   // 0..1023
        int side = id >> 9;                // 0=as, 1=ad
        int rem = id & 511;
        int h = rem >> 7, c = rem & 127;
        const float* av = side ? a_dst : a_src;
        float sum = 0.f;
#pragma unroll 8
        for (int k = 0; k < 64; k++) sum += W1[c * 256 + h * 64 + k] * av[h * 64 + k];
        (side ? wad : was)[h * 128 + c] = sum;
    }
}

// ---------------- x fp32 -> bf16 [N][128] ----------------
__global__ __launch_bounds__(256) void xb_kernel(const float* __restrict__ x,
                                                 ushort_t* __restrict__ xb, int total8) {
    int id = blockIdx.x * 256 + threadIdx.x;
    if (id >= total8) return;
    const float* g = x + (size_t)id * 8;
    float4 f0 = *(const float4*)g;
    float4 f1 = *(const float4*)(g + 4);
    uint4 o;
    o.x = pack2(f0.x, f0.y); o.y = pack2(f0.z, f0.w);
    o.z = pack2(f1.x, f1.y); o.w = pack2(f1.z, f1.w);
    ((uint4*)xb)[id] = o;
}

// ---------------- layer-1 attn coefficients from x-space: asn/adn[n][h] ----------------
// one node per wave; lane owns channel pair (2l, 2l+1)
__global__ __launch_bounds__(256) void asad_kernel(const ushort_t* __restrict__ xb,
                                                   const float* __restrict__ was,
                                                   const float* __restrict__ wad,
                                                   float* __restrict__ as_n,
                                                   float* __restrict__ ad_n, int N) {
    int n = blockIdx.x * 4 + (threadIdx.x >> 6);
    int lane = threadIdx.x & 63;
    if (n >= N) return;
    unsigned int xp = ((const unsigned int*)xb)[(size_t)n * 64 + lane];
    float x0 = lo16(xp), x1 = hi16(xp);
    float s[4], d[4];
#pragma unroll
    for (int h = 0; h < 4; h++) {
        float2 wa = ((const float2*)(was + h * 128))[lane];
        float2 wd = ((const float2*)(wad + h * 128))[lane];
        s[h] = x0 * wa.x + x1 * wa.y;
        d[h] = x0 * wd.x + x1 * wd.y;
    }
#pragma unroll
    for (int off = 32; off; off >>= 1) {
#pragma unroll
        for (int h = 0; h < 4; h++) {
            s[h] += __shfl_xor(s[h], off, 64);
            d[h] += __shfl_xor(d[h], off, 64);
        }
    }
    if (lane == 0) {
#pragma unroll
        for (int h = 0; h < 4; h++) {
            as_n[n * 4 + h] = s[h];
            ad_n[n * 4 + h] = d[h];
        }
    }
}

// ---------------- CSR build ----------------
__global__ __launch_bounds__(256) void degree_kernel(const int* __restrict__ ei_dst,
                                                     int* __restrict__ deg, int E, int Etot) {
    int e = blockIdx.x * 256 + threadIdx.x;
    if (e >= Etot) return;
    int d = (e < E) ? ei_dst[e] : (e - E);
    atomicAdd(&deg[d], 1);
}

__global__ __launch_bounds__(256) void partial_sum_kernel(const int* __restrict__ deg,
                                                          int* __restrict__ bsum, int n) {
    __shared__ int ws[4];
    int t = threadIdx.x;
    int i = blockIdx.x * 256 + t;
    int v = (i < n) ? deg[i] : 0;
#pragma unroll
    for (int off = 32; off; off >>= 1) v += __shfl_xor(v, off, 64);
    if ((t & 63) == 0) ws[t >> 6] = v;
    __syncthreads();
    if (t == 0) bsum[blockIdx.x] = ws[0] + ws[1] + ws[2] + ws[3];
}

__global__ __launch_bounds__(256) void scan_bsum_kernel(const int* __restrict__ bsum,
                                                        int* __restrict__ boff,
                                                        int* __restrict__ rowoff,
                                                        int nblk, int n) {
    __shared__ int sm[256];
    int t = threadIdx.x;
    int v = (t < nblk) ? bsum[t] : 0;
    sm[t] = v;
    __syncthreads();
#pragma unroll
    for (int off = 1; off < 256; off <<= 1) {
        int u = (t >= off) ? sm[t - off] : 0;
        __syncthreads();
        sm[t] += u;
        __syncthreads();
    }
    if (t < nblk) boff[t] = sm[t] - v;
    if (t == 255) rowoff[n] = sm[255];
}

__global__ __launch_bounds__(256) void block_scan_kernel(const int* __restrict__ deg,
                                                         const int* __restrict__ boff,
                                                         int* __restrict__ rowoff, int n) {
    __shared__ int sm[256];
    int t = threadIdx.x;
    int i = blockIdx.x * 256 + t;
    int v = (i < n) ? deg[i] : 0;
    sm[t] = v;
    __syncthreads();
#pragma unroll
    for (int off = 1; off < 256; off <<= 1) {
        int u = (t >= off) ? sm[t - off] : 0;
        __syncthreads();
        sm[t] += u;
        __syncthreads();
    }
    if (i < n) rowoff[i] = boff[blockIdx.x] + sm[t] - v;
}

__global__ __launch_bounds__(256) void copy_cursor_kernel(const int* __restrict__ rowoff,
                                                          int* __restrict__ cursor, int n) {
    int i = blockIdx.x * 256 + threadIdx.x;
    if (i < n) cursor[i] = rowoff[i];
}

__global__ __launch_bounds__(256) void scatter_kernel(const int* __restrict__ ei_src,
                                                      const int* __restrict__ ei_dst,
                                                      int* __restrict__ cursor,
                                                      int* __restrict__ ssrc, int E, int Etot) {
    int e = blockIdx.x * 256 + threadIdx.x;
    if (e >= Etot) return;
    int s, d;
    if (e < E) { s = ei_src[e]; d = ei_dst[e]; } else { s = d = e - E; }
    int pos = atomicAdd(&cursor[d], 1);
    ssrc[pos] = s;
}

// ---------------- layer-1 pre-aggregation in x-space (128-d rows, 4 heads) ----------------
// 1 dst/wave: lane = head*16 + l16; all 4 head-quads gather the SAME 256B row (coalesced dup);
// each lane accumulates its head's weighted sum of 8 channels. Output y[N][4][128] bf16,
// normalized by per-head denominator (bias/relu applied after the W1 GEMM).
__global__ __launch_bounds__(256) void agg_pre_kernel(const ushort_t* __restrict__ xb,
                                                      const float* __restrict__ as_n,
                                                      const float* __restrict__ ad_n,
                                                      const int* __restrict__ rowoff,
                                                      const int* __restrict__ ssrc,
                                                      ushort_t* __restrict__ y, int N) {
    const int tid = threadIdx.x;
    const int wv = tid >> 6, lane = tid & 63;
    const int dd = blockIdx.x * 4 + wv;
    if (dd >= N) return;
    const int h = lane >> 4, l16 = lane & 15;
    const int r0 = rowoff[dd], r1 = rowoff[dd + 1];
    const float adv = ad_n[dd * 4 + h];
    const uint4* xv = (const uint4*)xb;  // row = 16 uint4 (128 ch)
    float a0 = 0, a1 = 0, a2 = 0, a3 = 0, a4 = 0, a5 = 0, a6 = 0, a7 = 0, den = 0;
    for (int i = r0; i < r1; i += 8) {
        int s[8];
        float g[8];
        uint4 u[8];
#pragma unroll
        for (int j = 0; j < 8; j++) {
            int t = i + j;
            s[j] = ssrc[t < r1 ? t : r0];
        }
#pragma unroll
        for (int j = 0; j < 8; j++) g[j] = as_n[s[j] * 4 + h];
#pragma unroll
        for (int j = 0; j < 8; j++) u[j] = xv[(size_t)s[j] * 16 + l16];
#pragma unroll
        for (int j = 0; j < 8; j++) {
            float lg = g[j] + adv;
            lg = lg > 0.f ? lg : 0.2f * lg;
            float p = (i + j < r1) ? __expf(lg) : 0.f;
            den += p;
            a0 += p * lo16(u[j].x); a1 += p * hi16(u[j].x);
            a2 += p * lo16(u[j].y); a3 += p * hi16(u[j].y);
            a4 += p * lo16(u[j].z); a5 += p * hi16(u[j].z);
            a6 += p * lo16(u[j].w); a7 += p * hi16(u[j].w);
        }
    }
    float di = 1.f / (den + 1e-16f);
    uint4 o;
    o.x = pack2(a0 * di, a1 * di); o.y = pack2(a2 * di, a3 * di);
    o.z = pack2(a4 * di, a5 * di); o.w = pack2(a6 * di, a7 * di);
    ((uint4*)y)[(size_t)dd * 64 + h * 16 + l16] = o;
}

// ---------------- MFMA GEMM: C = A[M,K] @ WT[N2,K]^T  (A bf16, strided rows) ----------------
// BM=64, BN=64, BK=32; 256 thr = 4 waves. lda = A row stride (elems); A col base = by*aoff_mul.
// EPI: 0 = raw bf16 out, 1 = fp32 bias+relu out, 2 = bf16 bias+relu out.
template <int EPI>
__global__ __launch_bounds__(256) void gemm_mfma(const ushort_t* __restrict__ A,
                                                 const ushort_t* __restrict__ WT,
                                                 float* __restrict__ C,
                                                 ushort_t* __restrict__ Cb,
                                                 const float* __restrict__ bias,
                                                 int M, int K, int N2, int lda, int aoff_mul) {
    __shared__ ushort_t sA[64 * 32];  // 4 KB
    __shared__ ushort_t sB[64 * 32];  // 4 KB
    const int tid = threadIdx.x;
    const int wv = tid >> 6, lane = tid & 63;
    const int quad = lane >> 4, l16 = lane & 15;
    const int bm = blockIdx.x * 64, bn = blockIdx.y * 64;
    const int aoff = blockIdx.y * aoff_mul;
    const int srow = tid >> 2, skof = (tid & 3) * 8;
    f32x4 acc[4] = {};

    for (int k0 = 0; k0 < K; k0 += 32) {
        int gm = bm + srow;
        gm = gm < M ? gm : M - 1;  // clamp tail (dup read; epilogue masks)
        stage8(A + (size_t)gm * lda + aoff + k0 + skof, sA + srow * 32 + skof);
        stage8(WT + (size_t)(bn + srow) * K + k0 + skof, sB + srow * 32 + skof);
        __syncthreads();

        bf16x8 af = *(const bf16x8*)(sA + (wv * 16 + l16) * 32 + quad * 8);
#pragma unroll
        for (int j = 0; j < 4; j++) {
            bf16x8 bf = *(const bf16x8*)(sB + (j * 16 + l16) * 32 + quad * 8);
            acc[j] = __builtin_amdgcn_mfma_f32_16x16x32_bf16(af, bf, acc[j], 0, 0, 0);
        }
        __syncthreads();
    }

#pragma unroll
    for (int j = 0; j < 4; j++) {
        int col = bn + j * 16 + l16;
        float bv = (EPI != 0) ? bias[col] : 0.f;
#pragma unroll
        for (int r = 0; r < 4; r++) {
            int row = bm + wv * 16 + quad * 4 + r;
            if (row < M) {
                float v = acc[j][r];
                if (EPI == 1) {
                    v += bv;
                    v = v > 0.f ? v : 0.f;
                    C[(size_t)row * N2 + col] = v;
                } else if (EPI == 2) {
                    v += bv;
                    v = v > 0.f ? v : 0.f;
                    Cb[(size_t)row * N2 + col] = f2b(v);
                } else {
                    Cb[(size_t)row * N2 + col] = f2b(v);
                }
            }
        }
    }
}

// ---------------- attention coefficients (layers 2,3: from xl) ----------------
template <int CH>
__global__ __launch_bounds__(256) void attn_kernel(const ushort_t* __restrict__ xl,
                                                   const float* __restrict__ a_src,
                                                   const float* __restrict__ a_dst,
                                                   float* __restrict__ as_n,
                                                   float* __restrict__ ad_n, int N) {
    int n = blockIdx.x * 4 + (threadIdx.x >> 6);
    int lane = threadIdx.x & 63;
    if (n >= N) return;
    if (CH == 256) {
        ushort4 u = ((const ushort4*)xl)[(size_t)n * 64 + lane];
        float4 av = ((const float4*)a_src)[lane];
        float4 dv = ((const float4*)a_dst)[lane];
        float x0 = b2f(u.x), x1 = b2f(u.y), x2 = b2f(u.z), x3 = b2f(u.w);
        float s = x0 * av.x + x1 * av.y + x2 * av.z + x3 * av.w;
        float d = x0 * dv.x + x1 * dv.y + x2 * dv.z + x3 * dv.w;
#pragma unroll
        for (int off = 8; off; off >>= 1) {
            s += __shfl_xor(s, off, 64);
            d += __shfl_xor(d, off, 64);
        }
        if ((lane & 15) == 0) {
            int h = lane >> 4;
            as_n[n * 4 + h] = s;
            ad_n[n * 4 + h] = d;
        }
    } else {
        float xv = b2f(xl[(size_t)n * 64 + lane]);
        float s = xv * a_src[lane];
        float d = xv * a_dst[lane];
#pragma unroll
        for (int off = 32; off; off >>= 1) {
            s += __shfl_xor(s, off, 64);
            d += __shfl_xor(d, off, 64);
        }
        if (lane == 0) { as_n[n] = s; ad_n[n] = d; }
    }
}

// ---------------- per-dst softmax-weighted aggregation (layers 2,3) ----------------
template <int CH>
__global__ __launch_bounds__(256) void aggregate_kernel(const ushort_t* __restrict__ xl,
                                                        const float* __restrict__ as_n,
                                                        const float* __restrict__ ad_n,
                                                        const int* __restrict__ rowoff,
                                                        const int* __restrict__ ssrc,
                                                        const float* __restrict__ bias,
                                                        ushort_t* __restrict__ hout, int N) {
    const int tid = threadIdx.x;
    const int wv = tid >> 6, lane = tid & 63;
    const uint4* xv = (const uint4*)xl;
    if (CH == 256) {
        const int hw = lane >> 5, l32 = lane & 31;
        const int dd = blockIdx.x * 8 + wv * 2 + hw;
        if (dd >= N) return;
        const int h = l32 >> 3;
        const int r0 = rowoff[dd], r1 = rowoff[dd + 1];
        const float adv = ad_n[dd * 4 + h];
        float a0 = 0, a1 = 0, a2 = 0, a3 = 0, a4 = 0, a5 = 0, a6 = 0, a7 = 0, den = 0;
        for (int i = r0; i < r1; i += 8) {
            int s[8];
            float g[8];
            uint4 u[8];
#pragma unroll
            for (int j = 0; j < 8; j++) {
                int t = i + j;
                s[j] = ssrc[t < r1 ? t : r0];
            }
#pragma unroll
            for (int j = 0; j < 8; j++) g[j] = as_n[s[j] * 4 + h];
#pragma unroll
            for (int j = 0; j < 8; j++) u[j] = xv[(size_t)s[j] * 32 + l32];
#pragma unroll
            for (int j = 0; j < 8; j++) {
                float lg = g[j] + adv;
                lg = lg > 0.f ? lg : 0.2f * lg;
                float p = (i + j < r1) ? __expf(lg) : 0.f;
                den += p;
                a0 += p * lo16(u[j].x); a1 += p * hi16(u[j].x);
                a2 += p * lo16(u[j].y); a3 += p * hi16(u[j].y);
                a4 += p * lo16(u[j].z); a5 += p * hi16(u[j].z);
                a6 += p * lo16(u[j].w); a7 += p * hi16(u[j].w);
            }
        }
        float di = 1.f / (den + 1e-16f);
        float4 b0 = ((const float4*)bias)[l32 * 2];
        float4 b1 = ((const float4*)bias)[l32 * 2 + 1];
        float v0 = a0 * di + b0.x, v1 = a1 * di + b0.y;
        float v2 = a2 * di + b0.z, v3 = a3 * di + b0.w;
        float v4 = a4 * di + b1.x, v5 = a5 * di + b1.y;
        float v6 = a6 * di + b1.z, v7 = a7 * di + b1.w;
        v0 = v0 > 0.f ? v0 : 0.f; v1 = v1 > 0.f ? v1 : 0.f;
        v2 = v2 > 0.f ? v2 : 0.f; v3 = v3 > 0.f ? v3 : 0.f;
        v4 = v4 > 0.f ? v4 : 0.f; v5 = v5 > 0.f ? v5 : 0.f;
        v6 = v6 > 0.f ? v6 : 0.f; v7 = v7 > 0.f ? v7 : 0.f;
        uint4 o;
        o.x = pack2(v0, v1); o.y = pack2(v2, v3);
        o.z = pack2(v4, v5); o.w = pack2(v6, v7);
        ((uint4*)hout)[(size_t)dd * 32 + l32] = o;
    } else {
        const int grp = lane >> 3, l8 = lane & 7;
        const int dd = blockIdx.x * 32 + wv * 8 + grp;
        if (dd >= N) return;
        const int r0 = rowoff[dd], r1 = rowoff[dd + 1];
        const float adv = ad_n[dd];
        float a0 = 0, a1 = 0, a2 = 0, a3 = 0, a4 = 0, a5 = 0, a6 = 0, a7 = 0, den = 0;
        for (int i = r0; i < r1; i += 8) {
            int s[8];
            float g[8];
            uint4 u[8];
#pragma unroll
            for (int j = 0; j < 8; j++) {
                int t = i + j;
                s[j] = ssrc[t < r1 ? t : r0];
            }
#pragma unroll
            for (int j = 0; j < 8; j++) g[j] = as_n[s[j]];
#pragma unroll
            for (int j = 0; j < 8; j++) u[j] = xv[(size_t)s[j] * 8 + l8];
#pragma unroll
            for (int j = 0; j < 8; j++) {
                float lg = g[j] + adv;
                lg = lg > 0.f ? lg : 0.2f * lg;
                float p = (i + j < r1) ? __expf(lg) : 0.f;
                den += p;
                a0 += p * lo16(u[j].x); a1 += p * hi16(u[j].x);
                a2 += p * lo16(u[j].y); a3 += p * hi16(u[j].y);
                a4 += p * lo16(u[j].z); a5 += p * hi16(u[j].z);
                a6 += p * lo16(u[j].w); a7 += p * hi16(u[j].w);
            }
        }
        float di = 1.f / (den + 1e-16f);
        float4 b0 = ((const float4*)bias)[l8 * 2];
        float4 b1 = ((const float4*)bias)[l8 * 2 + 1];
        float v0 = a0 * di + b0.x, v1 = a1 * di + b0.y;
        float v2 = a2 * di + b0.z, v3 = a3 * di + b0.w;
        float v4 = a4 * di + b1.x, v5 = a5 * di + b1.y;
        float v6 = a6 * di + b1.z, v7 = a7 * di + b1.w;
        v0 = v0 > 0.f ? v0 : 0.f; v1 = v1 > 0.f ? v1 : 0.f;
        v2 = v2 > 0.f ? v2 : 0.f; v3 = v3 > 0.f ? v3 : 0.f;
        v4 = v4 > 0.f ? v4 : 0.f; v5 = v5 > 0.f ? v5 : 0.f;
        v6 = v6 > 0.f ? v6 : 0.f; v7 = v7 > 0.f ? v7 : 0.f;
        uint4 o;
        o.x = pack2(v0, v1); o.y = pack2(v2, v3);
        o.z = pack2(v4, v5); o.w = pack2(v6, v7);
        ((uint4*)hout)[(size_t)dd * 8 + l8] = o;
    }
}

extern "C" void kernel_launch(void* const* d_in, const int* in_sizes, int n_in,
                              void* d_out, int out_size, void* d_ws, size_t ws_size,
                              hipStream_t stream) {
    const int N = in_sizes[0] / 128;  // 50000
    const int E = in_sizes[1] / 2;    // 800000
    const int Etot = E + N;

    const float* x = (const float*)d_in[0];  // fp32 input
    const int* ei = (const int*)d_in[1];
    const int* ei_src = ei;
    const int* ei_dst = ei + E;
    float* out = (float*)d_out;  // fp32 output

    const float* as1 = (const float*)d_in[3];
    const float* ad1 = (const float*)d_in[4];
    const float* b1  = (const float*)d_in[5];
    const float* as2 = (const float*)d_in[7];
    const float* ad2 = (const float*)d_in[8];
    const float* b2  = (const float*)d_in[9];
    const float* as3 = (const float*)d_in[11];
    const float* ad3 = (const float*)d_in[12];
    const float* b3  = (const float*)d_in[13];
    const float* bfc = (const float*)d_in[15];

    // ---- workspace layout ----
    // bufY [N][512] bf16 (layer-1 pre-agg; bufX [N][256] aliases its first half — bufY is
    // dead after gemm1b, before bufX's first write in gemm2)
    ushort_t* bufY = (ushort_t*)d_ws;            // N*512 bf16 (51.2 MB)
    ushort_t* bufX = (ushort_t*)d_ws;            // alias: N*256 bf16
    ushort_t* bufH = bufY + (size_t)N * 512;     // N*256 bf16
    ushort_t* W1T  = bufH + (size_t)N * 256;     // 256x128 bf16
    ushort_t* W2T  = W1T + 32768;                // 256x256
    ushort_t* W3T  = W2T + 65536;                // 64x256
    ushort_t* WfcT = W3T + 16384;                // 512x64
    float* was  = (float*)(WfcT + 32768);        // 4x128
    float* wad  = was + 512;                     // 4x128
    float* asn  = wad + 512;                     // N*4
    float* adn  = asn + (size_t)N * 4;           // N*4
    int* deg    = (int*)(adn + (size_t)N * 4);   // N
    int* rowoff = deg + N;                       // N+1
    int* cursor = rowoff + N + 1;                // N
    int* ssrc   = cursor + N;                    // Etot
    int* bsum   = ssrc + Etot;                   // <=256
    int* boff   = bsum + 256;                    // <=256
    ushort_t* xb = (ushort_t*)(boff + 256);      // N*128 bf16 (12.8 MB)

    // weight transposes+converts (fp32 [K][N] -> bf16 [N][K])
    transpose_kernel<<<(128 * 256 + 255) / 256, 256, 0, stream>>>((const float*)d_in[2], W1T, 128, 256);
    transpose_kernel<<<(256 * 256 + 255) / 256, 256, 0, stream>>>((const float*)d_in[6], W2T, 256, 256);
    transpose_kernel<<<(256 * 64 + 255) / 256, 256, 0, stream>>>((const float*)d_in[10], W3T, 256, 64);
    transpose_kernel<<<(64 * 512 + 255) / 256, 256, 0, stream>>>((const float*)d_in[14], WfcT, 64, 512);
    prep_asad_kernel<<<1, 256, 0, stream>>>((const float*)d_in[2], as1, ad1, was, wad);
    xb_kernel<<<(N * 16 + 255) / 256, 256, 0, stream>>>(x, xb, N * 16);

    // CSR build
    hipMemsetAsync(deg, 0, (size_t)N * sizeof(int), stream);
    int eb = (Etot + 255) / 256;
    degree_kernel<<<eb, 256, 0, stream>>>(ei_dst, deg, E, Etot);
    const int NBLK = (N + 255) / 256;  // 196 (<= 256)
    partial_sum_kernel<<<NBLK, 256, 0, stream>>>(deg, bsum, N);
    scan_bsum_kernel<<<1, 256, 0, stream>>>(bsum, boff, rowoff, NBLK, N);
    block_scan_kernel<<<NBLK, 256, 0, stream>>>(deg, boff, rowoff, N);
    copy_cursor_kernel<<<NBLK, 256, 0, stream>>>(rowoff, cursor, N);
    scatter_kernel<<<eb, 256, 0, stream>>>(ei_src, ei_dst, cursor, ssrc, E, Etot);

    const int MB = (N + 63) / 64;  // 782
    int nb4 = (N + 3) / 4;
    int nb8 = (N + 7) / 8;
    int nb32 = (N + 31) / 32;

    // layer 1 (restructured): attn coeffs from x-space; aggregate x (256B rows); then W1
    asad_kernel<<<nb4, 256, 0, stream>>>(xb, was, wad, asn, adn, N);
    agg_pre_kernel<<<nb4, 256, 0, stream>>>(xb, asn, adn, rowoff, ssrc, bufY, N);
    // per-head GEMM: y[:,h,:] (K=128, lda=512) @ W1T rows h*64.. -> bufH cols h*64.. (+b1, relu)
    gemm_mfma<2><<<dim3(MB, 4), 256, 0, stream>>>(bufY, W1T, nullptr, bufH, b1, N, 128, 256, 512, 128);

    // layer 2
    gemm_mfma<0><<<dim3(MB, 4), 256, 0, stream>>>(bufH, W2T, nullptr, bufX, nullptr, N, 256, 256, 256, 0);
    attn_kernel<256><<<nb4, 256, 0, stream>>>(bufX, as2, ad2, asn, adn, N);
    aggregate_kernel<256><<<nb8, 256, 0, stream>>>(bufX, asn, adn, rowoff, ssrc, b2, bufH, N);

    // layer 3 (H=1, C=64)
    gemm_mfma<0><<<dim3(MB, 1), 256, 0, stream>>>(bufH, W3T, nullptr, bufX, nullptr, N, 256, 64, 256, 0);
    attn_kernel<64><<<nb4, 256, 0, stream>>>(bufX, as3, ad3, asn, adn, N);
    aggregate_kernel<64><<<nb32, 256, 0, stream>>>(bufX, asn, adn, rowoff, ssrc, b3, bufH, N);

    // final fc: relu(bufH[N,64] @ Wfc + bfc) -> fp32 out
    gemm_mfma<1><<<dim3(MB, 8), 256, 0, stream>>>(bufH, WfcT, out, nullptr, bfc, N, 64, 512, 64, 0);
}

// Round 6
// 521.573 us; speedup vs baseline: 1.0164x; 1.0164x over previous
//
#include <hip/hip_runtime.h>
#include <cstdint>
#include <cstddef>

typedef unsigned short ushort_t;
typedef __bf16 bf16x8 __attribute__((ext_vector_type(8)));
typedef float f32x4 __attribute__((ext_vector_type(4)));

__device__ __forceinline__ float b2f(ushort_t u) {
    return __uint_as_float(((unsigned int)u) << 16);
}
__device__ __forceinline__ ushort_t f2b(float f) {
    __bf16 h = (__bf16)f;  // RNE
    return *(ushort_t*)&h;
}
// bf16 pair unpack from packed uint (little-endian: lo ushort = even channel)
__device__ __forceinline__ float lo16(unsigned int u) { return __uint_as_float(u << 16); }
__device__ __forceinline__ float hi16(unsigned int u) { return __uint_as_float(u & 0xffff0000u); }
__device__ __forceinline__ unsigned int pack2(float a, float b) {
    return ((unsigned int)f2b(b) << 16) | (unsigned int)f2b(a);
}

// stage 8 contiguous elements into LDS as bf16 (overloaded on source type)
__device__ __forceinline__ void stage8(const float* __restrict__ g, ushort_t* s) {
    float4 f0 = *(const float4*)g;
    float4 f1 = *(const float4*)(g + 4);
    union { ushort_t u[8]; uint4 v; } t;
    t.u[0] = f2b(f0.x); t.u[1] = f2b(f0.y); t.u[2] = f2b(f0.z); t.u[3] = f2b(f0.w);
    t.u[4] = f2b(f1.x); t.u[5] = f2b(f1.y); t.u[6] = f2b(f1.z); t.u[7] = f2b(f1.w);
    *(uint4*)s = t.v;
}
__device__ __forceinline__ void stage8(const ushort_t* __restrict__ g, ushort_t* s) {
    *(float4*)s = *(const float4*)g;  // already bf16: raw 16B copy
}

// ---------------- all 4 weight transposes in one launch ----------------
// WT[n][k] = bf16(W[k][n]); segments: W1 128x256 | W2 256x256 | W3 256x64 | Wfc 64x512
__device__ __forceinline__ void tr_seg(int id, const float* __restrict__ W,
                                       ushort_t* __restrict__ WT, int K, int N2) {
    int n = id / K, k = id - n * K;
    WT[id] = f2b(W[k * N2 + n]);
}
__global__ __launch_bounds__(256) void transpose_all_kernel(const float* __restrict__ W1,
                                                            const float* __restrict__ W2,
                                                            const float* __restrict__ W3,
                                                            const float* __restrict__ Wfc,
                                                            ushort_t* __restrict__ W1T,
                                                            ushort_t* __restrict__ W2T,
                                                            ushort_t* __restrict__ W3T,
                                                            ushort_t* __restrict__ WfcT) {
    int id = blockIdx.x * 256 + threadIdx.x;
    if (id < 32768) { tr_seg(id, W1, W1T, 128, 256); return; }
    id -= 32768;
    if (id < 65536) { tr_seg(id, W2, W2T, 256, 256); return; }
    id -= 65536;
    if (id < 16384) { tr_seg(id, W3, W3T, 256, 64); return; }
    id -= 16384;
    if (id < 32768) { tr_seg(id, Wfc, WfcT, 64, 512); return; }
}

// ---------------- CSR build ----------------
__global__ __launch_bounds__(256) void degree_kernel(const int* __restrict__ ei_dst,
                                                     int* __restrict__ deg, int E, int Etot) {
    int e = blockIdx.x * 256 + threadIdx.x;
    if (e >= Etot) return;
    int d = (e < E) ? ei_dst[e] : (e - E);
    atomicAdd(&deg[d], 1);
}

__global__ __launch_bounds__(256) void partial_sum_kernel(const int* __restrict__ deg,
                                                          int* __restrict__ bsum, int n) {
    __shared__ int ws[4];
    int t = threadIdx.x;
    int i = blockIdx.x * 256 + t;
    int v = (i < n) ? deg[i] : 0;
#pragma unroll
    for (int off = 32; off; off >>= 1) v += __shfl_xor(v, off, 64);
    if ((t & 63) == 0) ws[t >> 6] = v;
    __syncthreads();
    if (t == 0) bsum[blockIdx.x] = ws[0] + ws[1] + ws[2] + ws[3];
}

__global__ __launch_bounds__(256) void scan_bsum_kernel(const int* __restrict__ bsum,
                                                        int* __restrict__ boff,
                                                        int* __restrict__ rowoff,
                                                        int nblk, int n) {
    __shared__ int sm[256];
    int t = threadIdx.x;
    int v = (t < nblk) ? bsum[t] : 0;
    sm[t] = v;
    __syncthreads();
#pragma unroll
    for (int off = 1; off < 256; off <<= 1) {
        int u = (t >= off) ? sm[t - off] : 0;
        __syncthreads();
        sm[t] += u;
        __syncthreads();
    }
    if (t < nblk) boff[t] = sm[t] - v;
    if (t == 255) rowoff[n] = sm[255];
}

// per-block inclusive scan + block offset -> exclusive rowoff[i]; also cursor[i]=rowoff[i]
__global__ __launch_bounds__(256) void block_scan_kernel(const int* __restrict__ deg,
                                                         const int* __restrict__ boff,
                                                         int* __restrict__ rowoff,
                                                         int* __restrict__ cursor, int n) {
    __shared__ int sm[256];
    int t = threadIdx.x;
    int i = blockIdx.x * 256 + t;
    int v = (i < n) ? deg[i] : 0;
    sm[t] = v;
    __syncthreads();
#pragma unroll
    for (int off = 1; off < 256; off <<= 1) {
        int u = (t >= off) ? sm[t - off] : 0;
        __syncthreads();
        sm[t] += u;
        __syncthreads();
    }
    if (i < n) {
        int r = boff[blockIdx.x] + sm[t] - v;
        rowoff[i] = r;
        cursor[i] = r;
    }
}

__global__ __launch_bounds__(256) void scatter_kernel(const int* __restrict__ ei_src,
                                                      const int* __restrict__ ei_dst,
                                                      int* __restrict__ cursor,
                                                      int* __restrict__ ssrc, int E, int Etot) {
    int e = blockIdx.x * 256 + threadIdx.x;
    if (e >= Etot) return;
    int s, d;
    if (e < E) { s = ei_src[e]; d = ei_dst[e]; } else { s = d = e - E; }
    int pos = atomicAdd(&cursor[d], 1);
    ssrc[pos] = s;
}

// ---------------- MFMA GEMM: C = A[M,K] @ WT[N2,K]^T ----------------
// BM=64, BN=NB (64 or 256), BK=32; 256 thr = 4 waves; wave w owns rows w*16..w*16+15.
// NB=256: one block covers all 256 cols -> A panel read exactly once (no by-reread).
// EPI: 0 = raw bf16 out, 1 = fp32 bias+relu out.
template <typename TA, int NB, int EPI>
__global__ __launch_bounds__(256) void gemm_mfma(const TA* __restrict__ A,
                                                 const ushort_t* __restrict__ WT,
                                                 float* __restrict__ C,
                                                 ushort_t* __restrict__ Cb,
                                                 const float* __restrict__ bias,
                                                 int M, int K, int N2) {
    __shared__ ushort_t sA[64 * 32];   // 4 KB
    __shared__ ushort_t sB[NB * 32];   // 4 or 16 KB
    const int tid = threadIdx.x;
    const int wv = tid >> 6, lane = tid & 63;
    const int quad = lane >> 4, l16 = lane & 15;
    const int bm = blockIdx.x * 64, bn = blockIdx.y * NB;
    const int srow = tid >> 2, skof = (tid & 3) * 8;
    f32x4 acc[NB / 16] = {};

    for (int k0 = 0; k0 < K; k0 += 32) {
        int gm = bm + srow;
        gm = gm < M ? gm : M - 1;  // clamp tail (dup read; epilogue masks)
        stage8(A + (size_t)gm * K + k0 + skof, sA + srow * 32 + skof);
#pragma unroll
        for (int r = 0; r < NB / 64; r++) {
            int brow = r * 64 + srow;
            stage8(WT + (size_t)(bn + brow) * K + k0 + skof, sB + brow * 32 + skof);
        }
        __syncthreads();

        bf16x8 af = *(const bf16x8*)(sA + (wv * 16 + l16) * 32 + quad * 8);
#pragma unroll
        for (int j = 0; j < NB / 16; j++) {
            bf16x8 bf = *(const bf16x8*)(sB + (j * 16 + l16) * 32 + quad * 8);
            acc[j] = __builtin_amdgcn_mfma_f32_16x16x32_bf16(af, bf, acc[j], 0, 0, 0);
        }
        __syncthreads();
    }

#pragma unroll
    for (int j = 0; j < NB / 16; j++) {
        int col = bn + j * 16 + l16;
        float bv = (EPI != 0) ? bias[col] : 0.f;
#pragma unroll
        for (int r = 0; r < 4; r++) {
            int row = bm + wv * 16 + quad * 4 + r;
            if (row < M) {
                float v = acc[j][r];
                if (EPI == 1) {
                    v += bv;
                    v = v > 0.f ? v : 0.f;
                    C[(size_t)row * N2 + col] = v;
                } else {
                    Cb[(size_t)row * N2 + col] = f2b(v);
                }
            }
        }
    }
}

// ---------------- attention coefficients ----------------
template <int CH>
__global__ __launch_bounds__(256) void attn_kernel(const ushort_t* __restrict__ xl,
                                                   const float* __restrict__ a_src,
                                                   const float* __restrict__ a_dst,
                                                   float* __restrict__ as_n,
                                                   float* __restrict__ ad_n, int N) {
    int n = blockIdx.x * 4 + (threadIdx.x >> 6);
    int lane = threadIdx.x & 63;
    if (n >= N) return;
    if (CH == 256) {
        ushort4 u = ((const ushort4*)xl)[(size_t)n * 64 + lane];
        float4 av = ((const float4*)a_src)[lane];
        float4 dv = ((const float4*)a_dst)[lane];
        float x0 = b2f(u.x), x1 = b2f(u.y), x2 = b2f(u.z), x3 = b2f(u.w);
        float s = x0 * av.x + x1 * av.y + x2 * av.z + x3 * av.w;
        float d = x0 * dv.x + x1 * dv.y + x2 * dv.z + x3 * dv.w;
#pragma unroll
        for (int off = 8; off; off >>= 1) {
            s += __shfl_xor(s, off, 64);
            d += __shfl_xor(d, off, 64);
        }
        if ((lane & 15) == 0) {
            int h = lane >> 4;
            as_n[n * 4 + h] = s;
            ad_n[n * 4 + h] = d;
        }
    } else {
        float xv = b2f(xl[(size_t)n * 64 + lane]);
        float s = xv * a_src[lane];
        float d = xv * a_dst[lane];
#pragma unroll
        for (int off = 32; off; off >>= 1) {
            s += __shfl_xor(s, off, 64);
            d += __shfl_xor(d, off, 64);
        }
        if (lane == 0) { as_n[n] = s; ad_n[n] = d; }
    }
}

// ---------------- per-dst softmax-weighted aggregation ----------------
// CH=256: 32 lanes/dst (lane=8ch dwordx4), 2 dst/wave. CH=64: 8 lanes/dst, 8 dst/wave.
// Clamp-and-zero padding: OOB slots clamp to r0 (L1-hit dup), p=0 kills contribution.
template <int CH>
__global__ __launch_bounds__(256) void aggregate_kernel(const ushort_t* __restrict__ xl,
                                                        const float* __restrict__ as_n,
                                                        const float* __restrict__ ad_n,
                                                        const int* __restrict__ rowoff,
                                                        const int* __restrict__ ssrc,
                                                        const float* __restrict__ bias,
                                                        ushort_t* __restrict__ hout, int N) {
    const int tid = threadIdx.x;
    const int wv = tid >> 6, lane = tid & 63;
    const uint4* xv = (const uint4*)xl;
    if (CH == 256) {
        const int hw = lane >> 5, l32 = lane & 31;
        const int dd = blockIdx.x * 8 + wv * 2 + hw;
        if (dd >= N) return;
        const int h = l32 >> 3;
        const int r0 = rowoff[dd], r1 = rowoff[dd + 1];
        const float adv = ad_n[dd * 4 + h];
        float a0 = 0, a1 = 0, a2 = 0, a3 = 0, a4 = 0, a5 = 0, a6 = 0, a7 = 0, den = 0;
        for (int i = r0; i < r1; i += 8) {
            int s[8];
            float g[8];
            uint4 u[8];
#pragma unroll
            for (int j = 0; j < 8; j++) {
                int t = i + j;
                s[j] = ssrc[t < r1 ? t : r0];
            }
#pragma unroll
            for (int j = 0; j < 8; j++) g[j] = as_n[s[j] * 4 + h];
#pragma unroll
            for (int j = 0; j < 8; j++) u[j] = xv[(size_t)s[j] * 32 + l32];
#pragma unroll
            for (int j = 0; j < 8; j++) {
                float lg = g[j] + adv;
                lg = lg > 0.f ? lg : 0.2f * lg;
                float p = (i + j < r1) ? __expf(lg) : 0.f;
                den += p;
                a0 += p * lo16(u[j].x); a1 += p * hi16(u[j].x);
                a2 += p * lo16(u[j].y); a3 += p * hi16(u[j].y);
                a4 += p * lo16(u[j].z); a5 += p * hi16(u[j].z);
                a6 += p * lo16(u[j].w); a7 += p * hi16(u[j].w);
            }
        }
        float di = 1.f / (den + 1e-16f);
        float4 b0 = ((const float4*)bias)[l32 * 2];
        float4 b1 = ((const float4*)bias)[l32 * 2 + 1];
        float v0 = a0 * di + b0.x, v1 = a1 * di + b0.y;
        float v2 = a2 * di + b0.z, v3 = a3 * di + b0.w;
        float v4 = a4 * di + b1.x, v5 = a5 * di + b1.y;
        float v6 = a6 * di + b1.z, v7 = a7 * di + b1.w;
        v0 = v0 > 0.f ? v0 : 0.f; v1 = v1 > 0.f ? v1 : 0.f;
        v2 = v2 > 0.f ? v2 : 0.f; v3 = v3 > 0.f ? v3 : 0.f;
        v4 = v4 > 0.f ? v4 : 0.f; v5 = v5 > 0.f ? v5 : 0.f;
        v6 = v6 > 0.f ? v6 : 0.f; v7 = v7 > 0.f ? v7 : 0.f;
        uint4 o;
        o.x = pack2(v0, v1); o.y = pack2(v2, v3);
        o.z = pack2(v4, v5); o.w = pack2(v6, v7);
        ((uint4*)hout)[(size_t)dd * 32 + l32] = o;
    } else {
        const int grp = lane >> 3, l8 = lane & 7;
        const int dd = blockIdx.x * 32 + wv * 8 + grp;
        if (dd >= N) return;
        const int r0 = rowoff[dd], r1 = rowoff[dd + 1];
        const float adv = ad_n[dd];
        float a0 = 0, a1 = 0, a2 = 0, a3 = 0, a4 = 0, a5 = 0, a6 = 0, a7 = 0, den = 0;
        for (int i = r0; i < r1; i += 8) {
            int s[8];
            float g[8];
            uint4 u[8];
#pragma unroll
            for (int j = 0; j < 8; j++) {
                int t = i + j;
                s[j] = ssrc[t < r1 ? t : r0];
            }
#pragma unroll
            for (int j = 0; j < 8; j++) g[j] = as_n[s[j]];
#pragma unroll
            for (int j = 0; j < 8; j++) u[j] = xv[(size_t)s[j] * 8 + l8];
#pragma unroll
            for (int j = 0; j < 8; j++) {
                float lg = g[j] + adv;
                lg = lg > 0.f ? lg : 0.2f * lg;
                float p = (i + j < r1) ? __expf(lg) : 0.f;
                den += p;
                a0 += p * lo16(u[j].x); a1 += p * hi16(u[j].x);
                a2 += p * lo16(u[j].y); a3 += p * hi16(u[j].y);
                a4 += p * lo16(u[j].z); a5 += p * hi16(u[j].z);
                a6 += p * lo16(u[j].w); a7 += p * hi16(u[j].w);
            }
        }
        float di = 1.f / (den + 1e-16f);
        float4 b0 = ((const float4*)bias)[l8 * 2];
        float4 b1 = ((const float4*)bias)[l8 * 2 + 1];
        float v0 = a0 * di + b0.x, v1 = a1 * di + b0.y;
        float v2 = a2 * di + b0.z, v3 = a3 * di + b0.w;
        float v4 = a4 * di + b1.x, v5 = a5 * di + b1.y;
        float v6 = a6 * di + b1.z, v7 = a7 * di + b1.w;
        v0 = v0 > 0.f ? v0 : 0.f; v1 = v1 > 0.f ? v1 : 0.f;
        v2 = v2 > 0.f ? v2 : 0.f; v3 = v3 > 0.f ? v3 : 0.f;
        v4 = v4 > 0.f ? v4 : 0.f; v5 = v5 > 0.f ? v5 : 0.f;
        v6 = v6 > 0.f ? v6 : 0.f; v7 = v7 > 0.f ? v7 : 0.f;
        uint4 o;
        o.x = pack2(v0, v1); o.y = pack2(v2, v3);
        o.z = pack2(v4, v5); o.w = pack2(v6, v7);
        ((uint4*)hout)[(size_t)dd * 8 + l8] = o;
    }
}

extern "C" void kernel_launch(void* const* d_in, const int* in_sizes, int n_in,
                              void* d_out, int out_size, void* d_ws, size_t ws_size,
                              hipStream_t stream) {
    const int N = in_sizes[0] / 128;  // 50000
    const int E = in_sizes[1] / 2;    // 800000
    const int Etot = E + N;

    const float* x = (const float*)d_in[0];  // fp32 input
    const int* ei = (const int*)d_in[1];
    const int* ei_src = ei;
    const int* ei_dst = ei + E;
    float* out = (float*)d_out;  // fp32 output

    const float* as1 = (const float*)d_in[3];
    const float* ad1 = (const float*)d_in[4];
    const float* b1  = (const float*)d_in[5];
    const float* as2 = (const float*)d_in[7];
    const float* ad2 = (const float*)d_in[8];
    const float* b2  = (const float*)d_in[9];
    const float* as3 = (const float*)d_in[11];
    const float* ad3 = (const float*)d_in[12];
    const float* b3  = (const float*)d_in[13];
    const float* bfc = (const float*)d_in[15];

    // ---- workspace layout (bf16 activations) ----
    ushort_t* bufX = (ushort_t*)d_ws;            // [N][256] bf16 (xl, GEMM out)
    ushort_t* bufH = bufX + (size_t)N * 256;     // [N][256] bf16 (agg out)
    ushort_t* W1T  = bufH + (size_t)N * 256;     // 256x128 bf16
    ushort_t* W2T  = W1T + 32768;                // 256x256
    ushort_t* W3T  = W2T + 65536;                // 64x256
    ushort_t* WfcT = W3T + 16384;                // 512x64
    float* asn = (float*)(WfcT + 32768);         // N*4
    float* adn = asn + (size_t)N * 4;            // N*4
    int* deg    = (int*)(adn + (size_t)N * 4);   // N
    int* rowoff = deg + N;                       // N+1
    int* cursor = rowoff + N + 1;                // N
    int* ssrc   = cursor + N;                    // Etot
    int* bsum   = ssrc + Etot;                   // <=256
    int* boff   = bsum + 256;                    // <=256

    // all weight transposes in one launch (147456 elems -> 576 blocks)
    transpose_all_kernel<<<576, 256, 0, stream>>>((const float*)d_in[2], (const float*)d_in[6],
                                                  (const float*)d_in[10], (const float*)d_in[14],
                                                  W1T, W2T, W3T, WfcT);

    // CSR build
    hipMemsetAsync(deg, 0, (size_t)N * sizeof(int), stream);
    int eb = (Etot + 255) / 256;
    degree_kernel<<<eb, 256, 0, stream>>>(ei_dst, deg, E, Etot);
    const int NBLK = (N + 255) / 256;  // 196 (<= 256)
    partial_sum_kernel<<<NBLK, 256, 0, stream>>>(deg, bsum, N);
    scan_bsum_kernel<<<1, 256, 0, stream>>>(bsum, boff, rowoff, NBLK, N);
    block_scan_kernel<<<NBLK, 256, 0, stream>>>(deg, boff, rowoff, cursor, N);
    scatter_kernel<<<eb, 256, 0, stream>>>(ei_src, ei_dst, cursor, ssrc, E, Etot);

    const int MB = (N + 63) / 64;  // 782
    int nb4 = (N + 3) / 4;
    int nb8 = (N + 7) / 8;
    int nb32 = (N + 31) / 32;

    // layer 1: x(fp32) @ W1 -> bufX(bf16); attn; aggregate -> bufH(bf16)
    gemm_mfma<float, 256, 0><<<dim3(MB, 1), 256, 0, stream>>>(x, W1T, nullptr, bufX, nullptr, N, 128, 256);
    attn_kernel<256><<<nb4, 256, 0, stream>>>(bufX, as1, ad1, asn, adn, N);
    aggregate_kernel<256><<<nb8, 256, 0, stream>>>(bufX, asn, adn, rowoff, ssrc, b1, bufH, N);

    // layer 2
    gemm_mfma<ushort_t, 256, 0><<<dim3(MB, 1), 256, 0, stream>>>(bufH, W2T, nullptr, bufX, nullptr, N, 256, 256);
    attn_kernel<256><<<nb4, 256, 0, stream>>>(bufX, as2, ad2, asn, adn, N);
    aggregate_kernel<256><<<nb8, 256, 0, stream>>>(bufX, asn, adn, rowoff, ssrc, b2, bufH, N);

    // layer 3 (H=1, C=64)
    gemm_mfma<ushort_t, 64, 0><<<dim3(MB, 1), 256, 0, stream>>>(bufH, W3T, nullptr, bufX, nullptr, N, 256, 64);
    attn_kernel<64><<<nb4, 256, 0, stream>>>(bufX, as3, ad3, asn, adn, N);
    aggregate_kernel<64><<<nb32, 256, 0, stream>>>(bufX, asn, adn, rowoff, ssrc, b3, bufH, N);

    // final fc: relu(bufH[N,64] @ Wfc + bfc) -> fp32 out (BN=256, by=2)
    gemm_mfma<ushort_t, 256, 1><<<dim3(MB, 2), 256, 0, stream>>>(bufH, WfcT, out, nullptr, bfc, N, 64, 512);
}

// Round 7
// 505.211 us; speedup vs baseline: 1.0493x; 1.0324x over previous
//
#include <hip/hip_runtime.h>
#include <cstdint>
#include <cstddef>

typedef unsigned short ushort_t;
typedef __bf16 bf16x8 __attribute__((ext_vector_type(8)));
typedef float f32x4 __attribute__((ext_vector_type(4)));

__device__ __forceinline__ float b2f(ushort_t u) {
    return __uint_as_float(((unsigned int)u) << 16);
}
__device__ __forceinline__ ushort_t f2b(float f) {
    __bf16 h = (__bf16)f;  // RNE
    return *(ushort_t*)&h;
}
// bf16 pair unpack from packed uint (little-endian: lo ushort = even channel)
__device__ __forceinline__ float lo16(unsigned int u) { return __uint_as_float(u << 16); }
__device__ __forceinline__ float hi16(unsigned int u) { return __uint_as_float(u & 0xffff0000u); }
__device__ __forceinline__ unsigned int pack2(float a, float b) {
    return ((unsigned int)f2b(b) << 16) | (unsigned int)f2b(a);
}

// ---------------- all 4 weight transposes in one launch ----------------
// WT[n][k] = bf16(W[k][n]); segments: W1 128x256 | W2 256x256 | W3 256x64 | Wfc 64x512
__device__ __forceinline__ void tr_seg(int id, const float* __restrict__ W,
                                       ushort_t* __restrict__ WT, int K, int N2) {
    int n = id / K, k = id - n * K;
    WT[id] = f2b(W[k * N2 + n]);
}
__global__ __launch_bounds__(256) void transpose_all_kernel(const float* __restrict__ W1,
                                                            const float* __restrict__ W2,
                                                            const float* __restrict__ W3,
                                                            const float* __restrict__ Wfc,
                                                            ushort_t* __restrict__ W1T,
                                                            ushort_t* __restrict__ W2T,
                                                            ushort_t* __restrict__ W3T,
                                                            ushort_t* __restrict__ WfcT) {
    int id = blockIdx.x * 256 + threadIdx.x;
    if (id < 32768) { tr_seg(id, W1, W1T, 128, 256); return; }
    id -= 32768;
    if (id < 65536) { tr_seg(id, W2, W2T, 256, 256); return; }
    id -= 65536;
    if (id < 16384) { tr_seg(id, W3, W3T, 256, 64); return; }
    id -= 16384;
    if (id < 32768) { tr_seg(id, Wfc, WfcT, 64, 512); return; }
}

// ---------------- x fp32 -> bf16 [N][128] (RNE, same as in-GEMM conversion) ----------------
__global__ __launch_bounds__(256) void xb_kernel(const float* __restrict__ x,
                                                 ushort_t* __restrict__ xb, int total8) {
    int id = blockIdx.x * 256 + threadIdx.x;
    if (id >= total8) return;
    const float* g = x + (size_t)id * 8;
    float4 f0 = *(const float4*)g;
    float4 f1 = *(const float4*)(g + 4);
    uint4 o;
    o.x = pack2(f0.x, f0.y); o.y = pack2(f0.z, f0.w);
    o.z = pack2(f1.x, f1.y); o.w = pack2(f1.z, f1.w);
    ((uint4*)xb)[id] = o;
}

// ---------------- CSR build ----------------
__global__ __launch_bounds__(256) void degree_kernel(const int* __restrict__ ei_dst,
                                                     int* __restrict__ deg, int E, int Etot) {
    int e = blockIdx.x * 256 + threadIdx.x;
    if (e >= Etot) return;
    int d = (e < E) ? ei_dst[e] : (e - E);
    atomicAdd(&deg[d], 1);
}

__global__ __launch_bounds__(256) void partial_sum_kernel(const int* __restrict__ deg,
                                                          int* __restrict__ bsum, int n) {
    __shared__ int ws[4];
    int t = threadIdx.x;
    int i = blockIdx.x * 256 + t;
    int v = (i < n) ? deg[i] : 0;
#pragma unroll
    for (int off = 32; off; off >>= 1) v += __shfl_xor(v, off, 64);
    if ((t & 63) == 0) ws[t >> 6] = v;
    __syncthreads();
    if (t == 0) bsum[blockIdx.x] = ws[0] + ws[1] + ws[2] + ws[3];
}

__global__ __launch_bounds__(256) void scan_bsum_kernel(const int* __restrict__ bsum,
                                                        int* __restrict__ boff,
                                                        int* __restrict__ rowoff,
                                                        int nblk, int n) {
    __shared__ int sm[256];
    int t = threadIdx.x;
    int v = (t < nblk) ? bsum[t] : 0;
    sm[t] = v;
    __syncthreads();
#pragma unroll
    for (int off = 1; off < 256; off <<= 1) {
        int u = (t >= off) ? sm[t - off] : 0;
        __syncthreads();
        sm[t] += u;
        __syncthreads();
    }
    if (t < nblk) boff[t] = sm[t] - v;
    if (t == 255) rowoff[n] = sm[255];
}

// per-block inclusive scan + block offset -> exclusive rowoff[i]; also cursor[i]=rowoff[i]
__global__ __launch_bounds__(256) void block_scan_kernel(const int* __restrict__ deg,
                                                         const int* __restrict__ boff,
                                                         int* __restrict__ rowoff,
                                                         int* __restrict__ cursor, int n) {
    __shared__ int sm[256];
    int t = threadIdx.x;
    int i = blockIdx.x * 256 + t;
    int v = (i < n) ? deg[i] : 0;
    sm[t] = v;
    __syncthreads();
#pragma unroll
    for (int off = 1; off < 256; off <<= 1) {
        int u = (t >= off) ? sm[t - off] : 0;
        __syncthreads();
        sm[t] += u;
        __syncthreads();
    }
    if (i < n) {
        int r = boff[blockIdx.x] + sm[t] - v;
        rowoff[i] = r;
        cursor[i] = r;
    }
}

__global__ __launch_bounds__(256) void scatter_kernel(const int* __restrict__ ei_src,
                                                      const int* __restrict__ ei_dst,
                                                      int* __restrict__ cursor,
                                                      int* __restrict__ ssrc, int E, int Etot) {
    int e = blockIdx.x * 256 + threadIdx.x;
    if (e >= Etot) return;
    int s, d;
    if (e < E) { s = ei_src[e]; d = ei_dst[e]; } else { s = d = e - E; }
    int pos = atomicAdd(&cursor[d], 1);
    ssrc[pos] = s;
}

// ---------------- 128x128 MFMA GEMM (m97-style structure, reg-staged) ----------------
// 256 thr = 4 waves in 2x2; wave (wr,wc) owns 64x64 quadrant; 4x4 16x16-frag accum.
// Per wave per K-step: 8 ds_read_b128 for 16 MFMAs (vs 17:16 in the BN=256 attempt).
// EPI: 0 = raw bf16 out, 1 = fp32 bias+relu out.
template <int EPI>
__global__ __launch_bounds__(256) void gemm128_mfma(const ushort_t* __restrict__ A,
                                                    const ushort_t* __restrict__ WT,
                                                    float* __restrict__ C,
                                                    ushort_t* __restrict__ Cb,
                                                    const float* __restrict__ bias,
                                                    int M, int K, int N2) {
    __shared__ ushort_t sA[128 * 32];  // 8 KB
    __shared__ ushort_t sB[128 * 32];  // 8 KB
    const int tid = threadIdx.x;
    const int wv = tid >> 6, lane = tid & 63;
    const int wr = wv >> 1, wc = wv & 1;
    const int quad = lane >> 4, l16 = lane & 15;
    const int bm = blockIdx.x * 128, bn = blockIdx.y * 128;
    const int sr0 = tid >> 2, sc = (tid & 3) * 8;  // staging: row=tid/4, 8-elem chunk
    const int sr1 = sr0 + 64;
    f32x4 acc[4][4] = {};

    int ga0 = bm + sr0; ga0 = ga0 < M ? ga0 : M - 1;  // clamp tail (dup read; masked store)
    int ga1 = bm + sr1; ga1 = ga1 < M ? ga1 : M - 1;
    const ushort_t* pa0 = A + (size_t)ga0 * K + sc;
    const ushort_t* pa1 = A + (size_t)ga1 * K + sc;
    const ushort_t* pb0 = WT + (size_t)(bn + sr0) * K + sc;
    const ushort_t* pb1 = WT + (size_t)(bn + sr1) * K + sc;

    for (int k0 = 0; k0 < K; k0 += 32) {
        *(float4*)(sA + sr0 * 32 + sc) = *(const float4*)(pa0 + k0);
        *(float4*)(sA + sr1 * 32 + sc) = *(const float4*)(pa1 + k0);
        *(float4*)(sB + sr0 * 32 + sc) = *(const float4*)(pb0 + k0);
        *(float4*)(sB + sr1 * 32 + sc) = *(const float4*)(pb1 + k0);
        __syncthreads();

        bf16x8 af[4], bfr[4];
#pragma unroll
        for (int m = 0; m < 4; m++)
            af[m] = *(const bf16x8*)(sA + (wr * 64 + m * 16 + l16) * 32 + quad * 8);
#pragma unroll
        for (int n = 0; n < 4; n++)
            bfr[n] = *(const bf16x8*)(sB + (wc * 64 + n * 16 + l16) * 32 + quad * 8);
#pragma unroll
        for (int m = 0; m < 4; m++)
#pragma unroll
            for (int n = 0; n < 4; n++)
                acc[m][n] = __builtin_amdgcn_mfma_f32_16x16x32_bf16(af[m], bfr[n], acc[m][n], 0, 0, 0);
        __syncthreads();
    }

#pragma unroll
    for (int n = 0; n < 4; n++) {
        int col = bn + wc * 64 + n * 16 + l16;
        float bv = (EPI == 1) ? bias[col] : 0.f;
#pragma unroll
        for (int m = 0; m < 4; m++) {
#pragma unroll
            for (int r = 0; r < 4; r++) {
                int row = bm + wr * 64 + m * 16 + quad * 4 + r;
                if (row < M) {
                    float v = acc[m][n][r];
                    if (EPI == 1) {
                        v += bv;
                        v = v > 0.f ? v : 0.f;
                        C[(size_t)row * N2 + col] = v;
                    } else {
                        Cb[(size_t)row * N2 + col] = f2b(v);
                    }
                }
            }
        }
    }
}

// ---------------- 64x64 MFMA GEMM (for N2=64 layer-3) ----------------
__global__ __launch_bounds__(256) void gemm64_mfma(const ushort_t* __restrict__ A,
                                                   const ushort_t* __restrict__ WT,
                                                   ushort_t* __restrict__ Cb,
                                                   int M, int K, int N2) {
    __shared__ ushort_t sA[64 * 32];  // 4 KB
    __shared__ ushort_t sB[64 * 32];  // 4 KB
    const int tid = threadIdx.x;
    const int wv = tid >> 6, lane = tid & 63;
    const int quad = lane >> 4, l16 = lane & 15;
    const int bm = blockIdx.x * 64;
    const int srow = tid >> 2, skof = (tid & 3) * 8;
    f32x4 acc[4] = {};

    int gm = bm + srow;
    gm = gm < M ? gm : M - 1;
    const ushort_t* pa = A + (size_t)gm * K + skof;
    const ushort_t* pb = WT + (size_t)srow * K + skof;

    for (int k0 = 0; k0 < K; k0 += 32) {
        *(float4*)(sA + srow * 32 + skof) = *(const float4*)(pa + k0);
        *(float4*)(sB + srow * 32 + skof) = *(const float4*)(pb + k0);
        __syncthreads();

        bf16x8 af = *(const bf16x8*)(sA + (wv * 16 + l16) * 32 + quad * 8);
#pragma unroll
        for (int j = 0; j < 4; j++) {
            bf16x8 bf = *(const bf16x8*)(sB + (j * 16 + l16) * 32 + quad * 8);
            acc[j] = __builtin_amdgcn_mfma_f32_16x16x32_bf16(af, bf, acc[j], 0, 0, 0);
        }
        __syncthreads();
    }

#pragma unroll
    for (int j = 0; j < 4; j++) {
        int col = j * 16 + l16;
#pragma unroll
        for (int r = 0; r < 4; r++) {
            int row = bm + wv * 16 + quad * 4 + r;
            if (row < M) Cb[(size_t)row * N2 + col] = f2b(acc[j][r]);
        }
    }
}

// ---------------- attention coefficients ----------------
template <int CH>
__global__ __launch_bounds__(256) void attn_kernel(const ushort_t* __restrict__ xl,
                                                   const float* __restrict__ a_src,
                                                   const float* __restrict__ a_dst,
                                                   float* __restrict__ as_n,
                                                   float* __restrict__ ad_n, int N) {
    int n = blockIdx.x * 4 + (threadIdx.x >> 6);
    int lane = threadIdx.x & 63;
    if (n >= N) return;
    if (CH == 256) {
        ushort4 u = ((const ushort4*)xl)[(size_t)n * 64 + lane];
        float4 av = ((const float4*)a_src)[lane];
        float4 dv = ((const float4*)a_dst)[lane];
        float x0 = b2f(u.x), x1 = b2f(u.y), x2 = b2f(u.z), x3 = b2f(u.w);
        float s = x0 * av.x + x1 * av.y + x2 * av.z + x3 * av.w;
        float d = x0 * dv.x + x1 * dv.y + x2 * dv.z + x3 * dv.w;
#pragma unroll
        for (int off = 8; off; off >>= 1) {
            s += __shfl_xor(s, off, 64);
            d += __shfl_xor(d, off, 64);
        }
        if ((lane & 15) == 0) {
            int h = lane >> 4;
            as_n[n * 4 + h] = s;
            ad_n[n * 4 + h] = d;
        }
    } else {
        float xv = b2f(xl[(size_t)n * 64 + lane]);
        float s = xv * a_src[lane];
        float d = xv * a_dst[lane];
#pragma unroll
        for (int off = 32; off; off >>= 1) {
            s += __shfl_xor(s, off, 64);
            d += __shfl_xor(d, off, 64);
        }
        if (lane == 0) { as_n[n] = s; ad_n[n] = d; }
    }
}

// ---------------- per-dst softmax-weighted aggregation ----------------
// CH=256: 32 lanes/dst (lane=8ch dwordx4), 2 dst/wave. CH=64: 8 lanes/dst, 8 dst/wave.
// Clamp-and-zero padding: OOB slots clamp to r0 (L1-hit dup), p=0 kills contribution.
template <int CH>
__global__ __launch_bounds__(256) void aggregate_kernel(const ushort_t* __restrict__ xl,
                                                        const float* __restrict__ as_n,
                                                        const float* __restrict__ ad_n,
                                                        const int* __restrict__ rowoff,
                                                        const int* __restrict__ ssrc,
                                                        const float* __restrict__ bias,
                                                        ushort_t* __restrict__ hout, int N) {
    const int tid = threadIdx.x;
    const int wv = tid >> 6, lane = tid & 63;
    const uint4* xv = (const uint4*)xl;
    if (CH == 256) {
        const int hw = lane >> 5, l32 = lane & 31;
        const int dd = blockIdx.x * 8 + wv * 2 + hw;
        if (dd >= N) return;
        const int h = l32 >> 3;
        const int r0 = rowoff[dd], r1 = rowoff[dd + 1];
        const float adv = ad_n[dd * 4 + h];
        float a0 = 0, a1 = 0, a2 = 0, a3 = 0, a4 = 0, a5 = 0, a6 = 0, a7 = 0, den = 0;
        for (int i = r0; i < r1; i += 8) {
            int s[8];
            float g[8];
            uint4 u[8];
#pragma unroll
            for (int j = 0; j < 8; j++) {
                int t = i + j;
                s[j] = ssrc[t < r1 ? t : r0];
            }
#pragma unroll
            for (int j = 0; j < 8; j++) g[j] = as_n[s[j] * 4 + h];
#pragma unroll
            for (int j = 0; j < 8; j++) u[j] = xv[(size_t)s[j] * 32 + l32];
#pragma unroll
            for (int j = 0; j < 8; j++) {
                float lg = g[j] + adv;
                lg = lg > 0.f ? lg : 0.2f * lg;
                float p = (i + j < r1) ? __expf(lg) : 0.f;
                den += p;
                a0 += p * lo16(u[j].x); a1 += p * hi16(u[j].x);
                a2 += p * lo16(u[j].y); a3 += p * hi16(u[j].y);
                a4 += p * lo16(u[j].z); a5 += p * hi16(u[j].z);
                a6 += p * lo16(u[j].w); a7 += p * hi16(u[j].w);
            }
        }
        float di = 1.f / (den + 1e-16f);
        float4 b0 = ((const float4*)bias)[l32 * 2];
        float4 b1 = ((const float4*)bias)[l32 * 2 + 1];
        float v0 = a0 * di + b0.x, v1 = a1 * di + b0.y;
        float v2 = a2 * di + b0.z, v3 = a3 * di + b0.w;
        float v4 = a4 * di + b1.x, v5 = a5 * di + b1.y;
        float v6 = a6 * di + b1.z, v7 = a7 * di + b1.w;
        v0 = v0 > 0.f ? v0 : 0.f; v1 = v1 > 0.f ? v1 : 0.f;
        v2 = v2 > 0.f ? v2 : 0.f; v3 = v3 > 0.f ? v3 : 0.f;
        v4 = v4 > 0.f ? v4 : 0.f; v5 = v5 > 0.f ? v5 : 0.f;
        v6 = v6 > 0.f ? v6 : 0.f; v7 = v7 > 0.f ? v7 : 0.f;
        uint4 o;
        o.x = pack2(v0, v1); o.y = pack2(v2, v3);
        o.z = pack2(v4, v5); o.w = pack2(v6, v7);
        ((uint4*)hout)[(size_t)dd * 32 + l32] = o;
    } else {
        const int grp = lane >> 3, l8 = lane & 7;
        const int dd = blockIdx.x * 32 + wv * 8 + grp;
        if (dd >= N) return;
        const int r0 = rowoff[dd], r1 = rowoff[dd + 1];
        const float adv = ad_n[dd];
        float a0 = 0, a1 = 0, a2 = 0, a3 = 0, a4 = 0, a5 = 0, a6 = 0, a7 = 0, den = 0;
        for (int i = r0; i < r1; i += 8) {
            int s[8];
            float g[8];
            uint4 u[8];
#pragma unroll
            for (int j = 0; j < 8; j++) {
                int t = i + j;
                s[j] = ssrc[t < r1 ? t : r0];
            }
#pragma unroll
            for (int j = 0; j < 8; j++) g[j] = as_n[s[j]];
#pragma unroll
            for (int j = 0; j < 8; j++) u[j] = xv[(size_t)s[j] * 8 + l8];
#pragma unroll
            for (int j = 0; j < 8; j++) {
                float lg = g[j] + adv;
                lg = lg > 0.f ? lg : 0.2f * lg;
                float p = (i + j < r1) ? __expf(lg) : 0.f;
                den += p;
                a0 += p * lo16(u[j].x); a1 += p * hi16(u[j].x);
                a2 += p * lo16(u[j].y); a3 += p * hi16(u[j].y);
                a4 += p * lo16(u[j].z); a5 += p * hi16(u[j].z);
                a6 += p * lo16(u[j].w); a7 += p * hi16(u[j].w);
            }
        }
        float di = 1.f / (den + 1e-16f);
        float4 b0 = ((const float4*)bias)[l8 * 2];
        float4 b1 = ((const float4*)bias)[l8 * 2 + 1];
        float v0 = a0 * di + b0.x, v1 = a1 * di + b0.y;
        float v2 = a2 * di + b0.z, v3 = a3 * di + b0.w;
        float v4 = a4 * di + b1.x, v5 = a5 * di + b1.y;
        float v6 = a6 * di + b1.z, v7 = a7 * di + b1.w;
        v0 = v0 > 0.f ? v0 : 0.f; v1 = v1 > 0.f ? v1 : 0.f;
        v2 = v2 > 0.f ? v2 : 0.f; v3 = v3 > 0.f ? v3 : 0.f;
        v4 = v4 > 0.f ? v4 : 0.f; v5 = v5 > 0.f ? v5 : 0.f;
        v6 = v6 > 0.f ? v6 : 0.f; v7 = v7 > 0.f ? v7 : 0.f;
        uint4 o;
        o.x = pack2(v0, v1); o.y = pack2(v2, v3);
        o.z = pack2(v4, v5); o.w = pack2(v6, v7);
        ((uint4*)hout)[(size_t)dd * 8 + l8] = o;
    }
}

extern "C" void kernel_launch(void* const* d_in, const int* in_sizes, int n_in,
                              void* d_out, int out_size, void* d_ws, size_t ws_size,
                              hipStream_t stream) {
    const int N = in_sizes[0] / 128;  // 50000
    const int E = in_sizes[1] / 2;    // 800000
    const int Etot = E + N;

    const float* x = (const float*)d_in[0];  // fp32 input
    const int* ei = (const int*)d_in[1];
    const int* ei_src = ei;
    const int* ei_dst = ei + E;
    float* out = (float*)d_out;  // fp32 output

    const float* as1 = (const float*)d_in[3];
    const float* ad1 = (const float*)d_in[4];
    const float* b1  = (const float*)d_in[5];
    const float* as2 = (const float*)d_in[7];
    const float* ad2 = (const float*)d_in[8];
    const float* b2  = (const float*)d_in[9];
    const float* as3 = (const float*)d_in[11];
    const float* ad3 = (const float*)d_in[12];
    const float* b3  = (const float*)d_in[13];
    const float* bfc = (const float*)d_in[15];

    // ---- workspace layout (bf16 activations) ----
    ushort_t* bufX = (ushort_t*)d_ws;            // [N][256] bf16 (xl, GEMM out)
    ushort_t* bufH = bufX + (size_t)N * 256;     // [N][256] bf16 (agg out)
    ushort_t* W1T  = bufH + (size_t)N * 256;     // 256x128 bf16
    ushort_t* W2T  = W1T + 32768;                // 256x256
    ushort_t* W3T  = W2T + 65536;                // 64x256
    ushort_t* WfcT = W3T + 16384;                // 512x64
    float* asn = (float*)(WfcT + 32768);         // N*4
    float* adn = asn + (size_t)N * 4;            // N*4
    int* deg    = (int*)(adn + (size_t)N * 4);   // N
    int* rowoff = deg + N;                       // N+1
    int* cursor = rowoff + N + 1;                // N
    int* ssrc   = cursor + N;                    // Etot
    int* bsum   = ssrc + Etot;                   // <=256
    int* boff   = bsum + 256;                    // <=256
    ushort_t* xb = (ushort_t*)(boff + 256);      // N*128 bf16 (12.8 MB)

    // weights + x conversion
    transpose_all_kernel<<<576, 256, 0, stream>>>((const float*)d_in[2], (const float*)d_in[6],
                                                  (const float*)d_in[10], (const float*)d_in[14],
                                                  W1T, W2T, W3T, WfcT);
    xb_kernel<<<(N * 16 + 255) / 256, 256, 0, stream>>>(x, xb, N * 16);

    // CSR build
    hipMemsetAsync(deg, 0, (size_t)N * sizeof(int), stream);
    int eb = (Etot + 255) / 256;
    degree_kernel<<<eb, 256, 0, stream>>>(ei_dst, deg, E, Etot);
    const int NBLK = (N + 255) / 256;  // 196 (<= 256)
    partial_sum_kernel<<<NBLK, 256, 0, stream>>>(deg, bsum, N);
    scan_bsum_kernel<<<1, 256, 0, stream>>>(bsum, boff, rowoff, NBLK, N);
    block_scan_kernel<<<NBLK, 256, 0, stream>>>(deg, boff, rowoff, cursor, N);
    scatter_kernel<<<eb, 256, 0, stream>>>(ei_src, ei_dst, cursor, ssrc, E, Etot);

    const int MB128 = (N + 127) / 128;  // 391
    const int MB64 = (N + 63) / 64;     // 782
    int nb4 = (N + 3) / 4;
    int nb8 = (N + 7) / 8;
    int nb32 = (N + 31) / 32;

    // layer 1: xb @ W1 -> bufX(bf16); attn; aggregate -> bufH(bf16)
    gemm128_mfma<0><<<dim3(MB128, 2), 256, 0, stream>>>(xb, W1T, nullptr, bufX, nullptr, N, 128, 256);
    attn_kernel<256><<<nb4, 256, 0, stream>>>(bufX, as1, ad1, asn, adn, N);
    aggregate_kernel<256><<<nb8, 256, 0, stream>>>(bufX, asn, adn, rowoff, ssrc, b1, bufH, N);

    // layer 2
    gemm128_mfma<0><<<dim3(MB128, 2), 256, 0, stream>>>(bufH, W2T, nullptr, bufX, nullptr, N, 256, 256);
    attn_kernel<256><<<nb4, 256, 0, stream>>>(bufX, as2, ad2, asn, adn, N);
    aggregate_kernel<256><<<nb8, 256, 0, stream>>>(bufX, asn, adn, rowoff, ssrc, b2, bufH, N);

    // layer 3 (H=1, C=64)
    gemm64_mfma<<<dim3(MB64, 1), 256, 0, stream>>>(bufH, W3T, bufX, N, 256, 64);
    attn_kernel<64><<<nb4, 256, 0, stream>>>(bufX, as3, ad3, asn, adn, N);
    aggregate_kernel<64><<<nb32, 256, 0, stream>>>(bufX, asn, adn, rowoff, ssrc, b3, bufH, N);

    // final fc: relu(bufH[N,64] @ Wfc + bfc) -> fp32 out
    gemm128_mfma<1><<<dim3(MB128, 4), 256, 0, stream>>>(bufH, WfcT, out, nullptr, bfc, N, 64, 512);
}

// Round 8
// 483.298 us; speedup vs baseline: 1.0969x; 1.0453x over previous
//
#include <hip/hip_runtime.h>
#include <cstdint>
#include <cstddef>

typedef unsigned short ushort_t;
typedef __bf16 bf16x8 __attribute__((ext_vector_type(8)));
typedef float f32x4 __attribute__((ext_vector_type(4)));

__device__ __forceinline__ float b2f(ushort_t u) {
    return __uint_as_float(((unsigned int)u) << 16);
}
__device__ __forceinline__ ushort_t f2b(float f) {
    __bf16 h = (__bf16)f;  // RNE
    return *(ushort_t*)&h;
}
// bf16 pair unpack from packed uint (little-endian: lo ushort = even channel)
__device__ __forceinline__ float lo16(unsigned int u) { return __uint_as_float(u << 16); }
__device__ __forceinline__ float hi16(unsigned int u) { return __uint_as_float(u & 0xffff0000u); }
__device__ __forceinline__ unsigned int pack2(float a, float b) {
    return ((unsigned int)f2b(b) << 16) | (unsigned int)f2b(a);
}

// stage 8 contiguous elements into LDS as bf16 (overloaded on source type)
__device__ __forceinline__ void stage8(const float* __restrict__ g, ushort_t* s) {
    float4 f0 = *(const float4*)g;
    float4 f1 = *(const float4*)(g + 4);
    union { ushort_t u[8]; uint4 v; } t;
    t.u[0] = f2b(f0.x); t.u[1] = f2b(f0.y); t.u[2] = f2b(f0.z); t.u[3] = f2b(f0.w);
    t.u[4] = f2b(f1.x); t.u[5] = f2b(f1.y); t.u[6] = f2b(f1.z); t.u[7] = f2b(f1.w);
    *(uint4*)s = t.v;
}
__device__ __forceinline__ void stage8(const ushort_t* __restrict__ g, ushort_t* s) {
    *(float4*)s = *(const float4*)g;  // already bf16: raw 16B copy
}

// ---------------- all 4 weight transposes + deg zeroing in one launch ----------------
// WT[n][k] = bf16(W[k][n]); segments: W1 128x256 | W2 256x256 | W3 256x64 | Wfc 64x512
__device__ __forceinline__ void tr_seg(int id, const float* __restrict__ W,
                                       ushort_t* __restrict__ WT, int K, int N2) {
    int n = id / K, k = id - n * K;
    WT[id] = f2b(W[k * N2 + n]);
}
__global__ __launch_bounds__(256) void transpose_all_kernel(const float* __restrict__ W1,
                                                            const float* __restrict__ W2,
                                                            const float* __restrict__ W3,
                                                            const float* __restrict__ Wfc,
                                                            ushort_t* __restrict__ W1T,
                                                            ushort_t* __restrict__ W2T,
                                                            ushort_t* __restrict__ W3T,
                                                            ushort_t* __restrict__ WfcT,
                                                            int* __restrict__ deg, int n) {
    int id = blockIdx.x * 256 + threadIdx.x;
    if (id < n) deg[id] = 0;  // fused memset (runs before degree_kernel in-stream)
    if (id < 32768) { tr_seg(id, W1, W1T, 128, 256); return; }
    id -= 32768;
    if (id < 65536) { tr_seg(id, W2, W2T, 256, 256); return; }
    id -= 65536;
    if (id < 16384) { tr_seg(id, W3, W3T, 256, 64); return; }
    id -= 16384;
    if (id < 32768) { tr_seg(id, Wfc, WfcT, 64, 512); return; }
}

// ---------------- CSR build ----------------
__global__ __launch_bounds__(256) void degree_kernel(const int* __restrict__ ei_dst,
                                                     int* __restrict__ deg, int E, int Etot) {
    int e = blockIdx.x * 256 + threadIdx.x;
    if (e >= Etot) return;
    int d = (e < E) ? ei_dst[e] : (e - E);
    atomicAdd(&deg[d], 1);
}

__global__ __launch_bounds__(256) void partial_sum_kernel(const int* __restrict__ deg,
                                                          int* __restrict__ bsum, int n) {
    __shared__ int ws[4];
    int t = threadIdx.x;
    int i = blockIdx.x * 256 + t;
    int v = (i < n) ? deg[i] : 0;
#pragma unroll
    for (int off = 32; off; off >>= 1) v += __shfl_xor(v, off, 64);
    if ((t & 63) == 0) ws[t >> 6] = v;
    __syncthreads();
    if (t == 0) bsum[blockIdx.x] = ws[0] + ws[1] + ws[2] + ws[3];
}

__global__ __launch_bounds__(256) void scan_bsum_kernel(const int* __restrict__ bsum,
                                                        int* __restrict__ boff,
                                                        int* __restrict__ rowoff,
                                                        int nblk, int n) {
    __shared__ int sm[256];
    int t = threadIdx.x;
    int v = (t < nblk) ? bsum[t] : 0;
    sm[t] = v;
    __syncthreads();
#pragma unroll
    for (int off = 1; off < 256; off <<= 1) {
        int u = (t >= off) ? sm[t - off] : 0;
        __syncthreads();
        sm[t] += u;
        __syncthreads();
    }
    if (t < nblk) boff[t] = sm[t] - v;
    if (t == 255) rowoff[n] = sm[255];
}

// per-block inclusive scan + block offset -> exclusive rowoff[i]; also cursor[i]=rowoff[i]
__global__ __launch_bounds__(256) void block_scan_kernel(const int* __restrict__ deg,
                                                         const int* __restrict__ boff,
                                                         int* __restrict__ rowoff,
                                                         int* __restrict__ cursor, int n) {
    __shared__ int sm[256];
    int t = threadIdx.x;
    int i = blockIdx.x * 256 + t;
    int v = (i < n) ? deg[i] : 0;
    sm[t] = v;
    __syncthreads();
#pragma unroll
    for (int off = 1; off < 256; off <<= 1) {
        int u = (t >= off) ? sm[t - off] : 0;
        __syncthreads();
        sm[t] += u;
        __syncthreads();
    }
    if (i < n) {
        int r = boff[blockIdx.x] + sm[t] - v;
        rowoff[i] = r;
        cursor[i] = r;
    }
}

__global__ __launch_bounds__(256) void scatter_kernel(const int* __restrict__ ei_src,
                                                      const int* __restrict__ ei_dst,
                                                      int* __restrict__ cursor,
                                                      int* __restrict__ ssrc, int E, int Etot) {
    int e = blockIdx.x * 256 + threadIdx.x;
    if (e >= Etot) return;
    int s, d;
    if (e < E) { s = ei_src[e]; d = ei_dst[e]; } else { s = d = e - E; }
    int pos = atomicAdd(&cursor[d], 1);
    ssrc[pos] = s;
}

// ---------------- 128x128 MFMA GEMM, optional fused attention epilogue ----------------
// 256 thr = 4 waves in 2x2; wave (wr,wc) owns 64x64 quadrant; 4x4 16x16-frag accum.
// EPI: 0 = raw bf16 out, 1 = fp32 bias+relu out,
//      2 = raw bf16 out + fused attn: wave (*,wc) holds ALL 64 channels of head by*2+wc
//          per row -> as/ad = per-lane 4 FMA + 4-step shfl reduce over l16.
template <typename TA, int EPI>
__global__ __launch_bounds__(256) void gemm128_mfma(const TA* __restrict__ A,
                                                    const ushort_t* __restrict__ WT,
                                                    float* __restrict__ C,
                                                    ushort_t* __restrict__ Cb,
                                                    const float* __restrict__ bias,
                                                    const float* __restrict__ a_src,
                                                    const float* __restrict__ a_dst,
                                                    float* __restrict__ as_n,
                                                    float* __restrict__ ad_n,
                                                    int M, int K, int N2) {
    __shared__ ushort_t sA[128 * 32];  // 8 KB
    __shared__ ushort_t sB[128 * 32];  // 8 KB
    const int tid = threadIdx.x;
    const int wv = tid >> 6, lane = tid & 63;
    const int wr = wv >> 1, wc = wv & 1;
    const int quad = lane >> 4, l16 = lane & 15;
    const int bm = blockIdx.x * 128, bn = blockIdx.y * 128;
    const int sr0 = tid >> 2, sc = (tid & 3) * 8;
    const int sr1 = sr0 + 64;
    f32x4 acc[4][4] = {};

    int ga0 = bm + sr0; ga0 = ga0 < M ? ga0 : M - 1;  // clamp tail (dup read; masked store)
    int ga1 = bm + sr1; ga1 = ga1 < M ? ga1 : M - 1;
    const TA* pa0 = A + (size_t)ga0 * K + sc;
    const TA* pa1 = A + (size_t)ga1 * K + sc;
    const ushort_t* pb0 = WT + (size_t)(bn + sr0) * K + sc;
    const ushort_t* pb1 = WT + (size_t)(bn + sr1) * K + sc;

    for (int k0 = 0; k0 < K; k0 += 32) {
        stage8(pa0 + k0, sA + sr0 * 32 + sc);
        stage8(pa1 + k0, sA + sr1 * 32 + sc);
        stage8(pb0 + k0, sB + sr0 * 32 + sc);
        stage8(pb1 + k0, sB + sr1 * 32 + sc);
        __syncthreads();

        bf16x8 af[4], bfr[4];
#pragma unroll
        for (int m = 0; m < 4; m++)
            af[m] = *(const bf16x8*)(sA + (wr * 64 + m * 16 + l16) * 32 + quad * 8);
#pragma unroll
        for (int n = 0; n < 4; n++)
            bfr[n] = *(const bf16x8*)(sB + (wc * 64 + n * 16 + l16) * 32 + quad * 8);
#pragma unroll
        for (int m = 0; m < 4; m++)
#pragma unroll
            for (int n = 0; n < 4; n++)
                acc[m][n] = __builtin_amdgcn_mfma_f32_16x16x32_bf16(af[m], bfr[n], acc[m][n], 0, 0, 0);
        __syncthreads();
    }

#pragma unroll
    for (int n = 0; n < 4; n++) {
        int col = bn + wc * 64 + n * 16 + l16;
        float bv = (EPI == 1) ? bias[col] : 0.f;
#pragma unroll
        for (int m = 0; m < 4; m++) {
#pragma unroll
            for (int r = 0; r < 4; r++) {
                int row = bm + wr * 64 + m * 16 + quad * 4 + r;
                if (row < M) {
                    float v = acc[m][n][r];
                    if (EPI == 1) {
                        v += bv;
                        v = v > 0.f ? v : 0.f;
                        C[(size_t)row * N2 + col] = v;
                    } else {
                        Cb[(size_t)row * N2 + col] = f2b(v);
                    }
                }
            }
        }
    }

    if (EPI == 2) {
        const int head = blockIdx.y * 2 + wc;
        float asv[4], adv[4];
#pragma unroll
        for (int n = 0; n < 4; n++) {
            asv[n] = a_src[head * 64 + n * 16 + l16];
            adv[n] = a_dst[head * 64 + n * 16 + l16];
        }
        float ps[4][4] = {}, pd[4][4] = {};
#pragma unroll
        for (int n = 0; n < 4; n++)
#pragma unroll
            for (int m = 0; m < 4; m++)
#pragma unroll
                for (int r = 0; r < 4; r++) {
                    ps[m][r] += acc[m][n][r] * asv[n];
                    pd[m][r] += acc[m][n][r] * adv[n];
                }
#pragma unroll
        for (int off = 1; off < 16; off <<= 1)
#pragma unroll
            for (int m = 0; m < 4; m++)
#pragma unroll
                for (int r = 0; r < 4; r++) {
                    ps[m][r] += __shfl_xor(ps[m][r], off, 64);
                    pd[m][r] += __shfl_xor(pd[m][r], off, 64);
                }
        if (l16 == 0) {
#pragma unroll
            for (int m = 0; m < 4; m++)
#pragma unroll
                for (int r = 0; r < 4; r++) {
                    int row = bm + wr * 64 + m * 16 + quad * 4 + r;
                    if (row < M) {
                        as_n[row * 4 + head] = ps[m][r];
                        ad_n[row * 4 + head] = pd[m][r];
                    }
                }
        }
    }
}

// ---------------- 64x64 MFMA GEMM with fused attn (layer-3: N2=64, 1 head) ----------------
__global__ __launch_bounds__(256) void gemm64_mfma(const ushort_t* __restrict__ A,
                                                   const ushort_t* __restrict__ WT,
                                                   ushort_t* __restrict__ Cb,
                                                   const float* __restrict__ a_src,
                                                   const float* __restrict__ a_dst,
                                                   float* __restrict__ as_n,
                                                   float* __restrict__ ad_n,
                                                   int M, int K, int N2) {
    __shared__ ushort_t sA[64 * 32];  // 4 KB
    __shared__ ushort_t sB[64 * 32];  // 4 KB
    const int tid = threadIdx.x;
    const int wv = tid >> 6, lane = tid & 63;
    const int quad = lane >> 4, l16 = lane & 15;
    const int bm = blockIdx.x * 64;
    const int srow = tid >> 2, skof = (tid & 3) * 8;
    f32x4 acc[4] = {};

    int gm = bm + srow;
    gm = gm < M ? gm : M - 1;
    const ushort_t* pa = A + (size_t)gm * K + skof;
    const ushort_t* pb = WT + (size_t)srow * K + skof;

    for (int k0 = 0; k0 < K; k0 += 32) {
        *(float4*)(sA + srow * 32 + skof) = *(const float4*)(pa + k0);
        *(float4*)(sB + srow * 32 + skof) = *(const float4*)(pb + k0);
        __syncthreads();

        bf16x8 af = *(const bf16x8*)(sA + (wv * 16 + l16) * 32 + quad * 8);
#pragma unroll
        for (int j = 0; j < 4; j++) {
            bf16x8 bf = *(const bf16x8*)(sB + (j * 16 + l16) * 32 + quad * 8);
            acc[j] = __builtin_amdgcn_mfma_f32_16x16x32_bf16(af, bf, acc[j], 0, 0, 0);
        }
        __syncthreads();
    }

#pragma unroll
    for (int j = 0; j < 4; j++) {
        int col = j * 16 + l16;
#pragma unroll
        for (int r = 0; r < 4; r++) {
            int row = bm + wv * 16 + quad * 4 + r;
            if (row < M) Cb[(size_t)row * N2 + col] = f2b(acc[j][r]);
        }
    }

    // fused attn: the wave's 4 j-frags x 16 lanes span all 64 cols (single head)
    float asv[4], adv[4];
#pragma unroll
    for (int j = 0; j < 4; j++) {
        asv[j] = a_src[j * 16 + l16];
        adv[j] = a_dst[j * 16 + l16];
    }
    float ps[4] = {}, pd[4] = {};
#pragma unroll
    for (int j = 0; j < 4; j++)
#pragma unroll
        for (int r = 0; r < 4; r++) {
            ps[r] += acc[j][r] * asv[j];
            pd[r] += acc[j][r] * adv[j];
        }
#pragma unroll
    for (int off = 1; off < 16; off <<= 1)
#pragma unroll
        for (int r = 0; r < 4; r++) {
            ps[r] += __shfl_xor(ps[r], off, 64);
            pd[r] += __shfl_xor(pd[r], off, 64);
        }
    if (l16 == 0) {
#pragma unroll
        for (int r = 0; r < 4; r++) {
            int row = bm + wv * 16 + quad * 4 + r;
            if (row < M) {
                as_n[row] = ps[r];
                ad_n[row] = pd[r];
            }
        }
    }
}

// ---------------- per-dst softmax-weighted aggregation ----------------
// CH=256: 32 lanes/dst (lane=8ch dwordx4), 2 dst/wave. CH=64: 8 lanes/dst, 8 dst/wave.
// Clamp-and-zero padding: OOB slots clamp to r0 (L1-hit dup), p=0 kills contribution.
template <int CH>
__global__ __launch_bounds__(256) void aggregate_kernel(const ushort_t* __restrict__ xl,
                                                        const float* __restrict__ as_n,
                                                        const float* __restrict__ ad_n,
                                                        const int* __restrict__ rowoff,
                                                        const int* __restrict__ ssrc,
                                                        const float* __restrict__ bias,
                                                        ushort_t* __restrict__ hout, int N) {
    const int tid = threadIdx.x;
    const int wv = tid >> 6, lane = tid & 63;
    const uint4* xv = (const uint4*)xl;
    if (CH == 256) {
        const int hw = lane >> 5, l32 = lane & 31;
        const int dd = blockIdx.x * 8 + wv * 2 + hw;
        if (dd >= N) return;
        const int h = l32 >> 3;
        const int r0 = rowoff[dd], r1 = rowoff[dd + 1];
        const float adv = ad_n[dd * 4 + h];
        float a0 = 0, a1 = 0, a2 = 0, a3 = 0, a4 = 0, a5 = 0, a6 = 0, a7 = 0, den = 0;
        for (int i = r0; i < r1; i += 8) {
            int s[8];
            float g[8];
            uint4 u[8];
#pragma unroll
            for (int j = 0; j < 8; j++) {
                int t = i + j;
                s[j] = ssrc[t < r1 ? t : r0];
            }
#pragma unroll
            for (int j = 0; j < 8; j++) g[j] = as_n[s[j] * 4 + h];
#pragma unroll
            for (int j = 0; j < 8; j++) u[j] = xv[(size_t)s[j] * 32 + l32];
#pragma unroll
            for (int j = 0; j < 8; j++) {
                float lg = g[j] + adv;
                lg = lg > 0.f ? lg : 0.2f * lg;
                float p = (i + j < r1) ? __expf(lg) : 0.f;
                den += p;
                a0 += p * lo16(u[j].x); a1 += p * hi16(u[j].x);
                a2 += p * lo16(u[j].y); a3 += p * hi16(u[j].y);
                a4 += p * lo16(u[j].z); a5 += p * hi16(u[j].z);
                a6 += p * lo16(u[j].w); a7 += p * hi16(u[j].w);
            }
        }
        float di = 1.f / (den + 1e-16f);
        float4 b0 = ((const float4*)bias)[l32 * 2];
        float4 b1 = ((const float4*)bias)[l32 * 2 + 1];
        float v0 = a0 * di + b0.x, v1 = a1 * di + b0.y;
        float v2 = a2 * di + b0.z, v3 = a3 * di + b0.w;
        float v4 = a4 * di + b1.x, v5 = a5 * di + b1.y;
        float v6 = a6 * di + b1.z, v7 = a7 * di + b1.w;
        v0 = v0 > 0.f ? v0 : 0.f; v1 = v1 > 0.f ? v1 : 0.f;
        v2 = v2 > 0.f ? v2 : 0.f; v3 = v3 > 0.f ? v3 : 0.f;
        v4 = v4 > 0.f ? v4 : 0.f; v5 = v5 > 0.f ? v5 : 0.f;
        v6 = v6 > 0.f ? v6 : 0.f; v7 = v7 > 0.f ? v7 : 0.f;
        uint4 o;
        o.x = pack2(v0, v1); o.y = pack2(v2, v3);
        o.z = pack2(v4, v5); o.w = pack2(v6, v7);
        ((uint4*)hout)[(size_t)dd * 32 + l32] = o;
    } else {
        const int grp = lane >> 3, l8 = lane & 7;
        const int dd = blockIdx.x * 32 + wv * 8 + grp;
        if (dd >= N) return;
        const int r0 = rowoff[dd], r1 = rowoff[dd + 1];
        const float adv = ad_n[dd];
        float a0 = 0, a1 = 0, a2 = 0, a3 = 0, a4 = 0, a5 = 0, a6 = 0, a7 = 0, den = 0;
        for (int i = r0; i < r1; i += 8) {
            int s[8];
            float g[8];
            uint4 u[8];
#pragma unroll
            for (int j = 0; j < 8; j++) {
                int t = i + j;
                s[j] = ssrc[t < r1 ? t : r0];
            }
#pragma unroll
            for (int j = 0; j < 8; j++) g[j] = as_n[s[j]];
#pragma unroll
            for (int j = 0; j < 8; j++) u[j] = xv[(size_t)s[j] * 8 + l8];
#pragma unroll
            for (int j = 0; j < 8; j++) {
                float lg = g[j] + adv;
                lg = lg > 0.f ? lg : 0.2f * lg;
                float p = (i + j < r1) ? __expf(lg) : 0.f;
                den += p;
                a0 += p * lo16(u[j].x); a1 += p * hi16(u[j].x);
                a2 += p * lo16(u[j].y); a3 += p * hi16(u[j].y);
                a4 += p * lo16(u[j].z); a5 += p * hi16(u[j].z);
                a6 += p * lo16(u[j].w); a7 += p * hi16(u[j].w);
            }
        }
        float di = 1.f / (den + 1e-16f);
        float4 b0 = ((const float4*)bias)[l8 * 2];
        float4 b1 = ((const float4*)bias)[l8 * 2 + 1];
        float v0 = a0 * di + b0.x, v1 = a1 * di + b0.y;
        float v2 = a2 * di + b0.z, v3 = a3 * di + b0.w;
        float v4 = a4 * di + b1.x, v5 = a5 * di + b1.y;
        float v6 = a6 * di + b1.z, v7 = a7 * di + b1.w;
        v0 = v0 > 0.f ? v0 : 0.f; v1 = v1 > 0.f ? v1 : 0.f;
        v2 = v2 > 0.f ? v2 : 0.f; v3 = v3 > 0.f ? v3 : 0.f;
        v4 = v4 > 0.f ? v4 : 0.f; v5 = v5 > 0.f ? v5 : 0.f;
        v6 = v6 > 0.f ? v6 : 0.f; v7 = v7 > 0.f ? v7 : 0.f;
        uint4 o;
        o.x = pack2(v0, v1); o.y = pack2(v2, v3);
        o.z = pack2(v4, v5); o.w = pack2(v6, v7);
        ((uint4*)hout)[(size_t)dd * 8 + l8] = o;
    }
}

extern "C" void kernel_launch(void* const* d_in, const int* in_sizes, int n_in,
                              void* d_out, int out_size, void* d_ws, size_t ws_size,
                              hipStream_t stream) {
    const int N = in_sizes[0] / 128;  // 50000
    const int E = in_sizes[1] / 2;    // 800000
    const int Etot = E + N;

    const float* x = (const float*)d_in[0];  // fp32 input
    const int* ei = (const int*)d_in[1];
    const int* ei_src = ei;
    const int* ei_dst = ei + E;
    float* out = (float*)d_out;  // fp32 output

    const float* as1 = (const float*)d_in[3];
    const float* ad1 = (const float*)d_in[4];
    const float* b1  = (const float*)d_in[5];
    const float* as2 = (const float*)d_in[7];
    const float* ad2 = (const float*)d_in[8];
    const float* b2  = (const float*)d_in[9];
    const float* as3 = (const float*)d_in[11];
    const float* ad3 = (const float*)d_in[12];
    const float* b3  = (const float*)d_in[13];
    const float* bfc = (const float*)d_in[15];

    // ---- workspace layout (bf16 activations) ----
    ushort_t* bufX = (ushort_t*)d_ws;            // [N][256] bf16 (xl, GEMM out)
    ushort_t* bufH = bufX + (size_t)N * 256;     // [N][256] bf16 (agg out)
    ushort_t* W1T  = bufH + (size_t)N * 256;     // 256x128 bf16
    ushort_t* W2T  = W1T + 32768;                // 256x256
    ushort_t* W3T  = W2T + 65536;                // 64x256
    ushort_t* WfcT = W3T + 16384;                // 512x64
    float* asn = (float*)(WfcT + 32768);         // N*4
    float* adn = asn + (size_t)N * 4;            // N*4
    int* deg    = (int*)(adn + (size_t)N * 4);   // N
    int* rowoff = deg + N;                       // N+1
    int* cursor = rowoff + N + 1;                // N
    int* ssrc   = cursor + N;                    // Etot
    int* bsum   = ssrc + Etot;                   // <=256
    int* boff   = bsum + 256;                    // <=256

    // weight transposes + deg zeroing in one launch
    transpose_all_kernel<<<576, 256, 0, stream>>>((const float*)d_in[2], (const float*)d_in[6],
                                                  (const float*)d_in[10], (const float*)d_in[14],
                                                  W1T, W2T, W3T, WfcT, deg, N);

    // CSR build
    int eb = (Etot + 255) / 256;
    degree_kernel<<<eb, 256, 0, stream>>>(ei_dst, deg, E, Etot);
    const int NBLK = (N + 255) / 256;  // 196 (<= 256)
    partial_sum_kernel<<<NBLK, 256, 0, stream>>>(deg, bsum, N);
    scan_bsum_kernel<<<1, 256, 0, stream>>>(bsum, boff, rowoff, NBLK, N);
    block_scan_kernel<<<NBLK, 256, 0, stream>>>(deg, boff, rowoff, cursor, N);
    scatter_kernel<<<eb, 256, 0, stream>>>(ei_src, ei_dst, cursor, ssrc, E, Etot);

    const int MB128 = (N + 127) / 128;  // 391
    const int MB64 = (N + 63) / 64;     // 782
    int nb8 = (N + 7) / 8;
    int nb32 = (N + 31) / 32;

    // layer 1: x(fp32) @ W1 -> bufX(bf16) + fused attn; aggregate -> bufH(bf16)
    gemm128_mfma<float, 2><<<dim3(MB128, 2), 256, 0, stream>>>(
        x, W1T, nullptr, bufX, nullptr, as1, ad1, asn, adn, N, 128, 256);
    aggregate_kernel<256><<<nb8, 256, 0, stream>>>(bufX, asn, adn, rowoff, ssrc, b1, bufH, N);

    // layer 2
    gemm128_mfma<ushort_t, 2><<<dim3(MB128, 2), 256, 0, stream>>>(
        bufH, W2T, nullptr, bufX, nullptr, as2, ad2, asn, adn, N, 256, 256);
    aggregate_kernel<256><<<nb8, 256, 0, stream>>>(bufX, asn, adn, rowoff, ssrc, b2, bufH, N);

    // layer 3 (H=1, C=64) + fused attn
    gemm64_mfma<<<dim3(MB64, 1), 256, 0, stream>>>(bufH, W3T, bufX, as3, ad3, asn, adn, N, 256, 64);
    aggregate_kernel<64><<<nb32, 256, 0, stream>>>(bufX, asn, adn, rowoff, ssrc, b3, bufH, N);

    // final fc: relu(bufH[N,64] @ Wfc + bfc) -> fp32 out
    gemm128_mfma<ushort_t, 1><<<dim3(MB128, 4), 256, 0, stream>>>(
        bufH, WfcT, out, nullptr, bfc, nullptr, nullptr, nullptr, nullptr, N, 64, 512);
}